// Round 12
// baseline (252.454 us; speedup 1.0000x reference)
//
#include <hip/hip_runtime.h>
#include <hip/hip_bf16.h>
#include <cmath>

typedef __attribute__((ext_vector_type(8))) short short8;
typedef __attribute__((ext_vector_type(4))) float f32x4;

#define SM_CH 16   // scores stats chunks: 4000 rows / 256-row blocks -> 16
#define WCH   32   // softmax write-pass chunking

__device__ inline ushort f2bf(float x) {
    union { float f; unsigned u; } v; v.f = x;
    unsigned r = v.u + 0x7FFF + ((v.u >> 16) & 1);   // RNE
    return (ushort)(r >> 16);
}

__device__ inline void split2(float x, ushort& hi, ushort& lo) {
    union { float f; unsigned u; } v; v.f = x;
    hi = (ushort)(v.u >> 16);
    union { float f; unsigned u; } h; h.u = v.u & 0xFFFF0000u;
    union { float f; unsigned u; } d; d.f = x - h.f;
    lo = (ushort)(d.u >> 16);
}

// byte offset within one [rows x 128B] LDS plane, XOR-swizzled (T2).
__device__ inline int swz(int row, int byte_in_row) {
    return row * 128 + (byte_in_row ^ ((row & 7) << 4));
}

// async global->LDS, 16B/lane; lds base wave-uniform, HW adds lane*16.
__device__ inline void gload16(const void* g, void* lds) {
    __builtin_amdgcn_global_load_lds(
        (const __attribute__((address_space(1))) unsigned int*)g,
        (__attribute__((address_space(3))) unsigned int*)lds, 16, 0, 0);
}

// T1: bijective XCD-aware block remap (requires nwg % 8 == 0).
__device__ inline void xcd_remap(int& bx, int& by, int& bz) {
    unsigned nx = gridDim.x, ny = gridDim.y;
    unsigned nwg = nx * ny * gridDim.z;
    unsigned id = blockIdx.x + nx * (blockIdx.y + ny * blockIdx.z);
    unsigned q = nwg >> 3;
    unsigned s = (id & 7) * q + (id >> 3);
    bx = s % nx; unsigned r = s / nx;
    by = r % ny; bz = r / ny;
}

// ---------------------------------------------------------------------------
// scores GEMM v2 (R9-proven): weights[b] = labelHL @ projHL[b]^T, 3-term split.
// BK=32, paired-plane LDS rows: [hi 32k | lo 32k] = 128B. All 4 planes
// staged ONCE per K-tile (64KB, dbuf in 128KB LDS); 24 ds_read feed 96 MFMA.
// Fused per-column (max,sum) partials over the block's 256 rows.
// ---------------------------------------------------------------------------
__global__ __launch_bounds__(512, 2) void mfma_sc2(
    const ushort* __restrict__ AH, const ushort* __restrict__ AL,
    const ushort* __restrict__ BH, const ushort* __restrict__ BL,
    float* __restrict__ Cb, float* __restrict__ pmo, float* __restrict__ pso,
    int M, int N, long long sB, long long sC)
{
    extern __shared__ char smem[];
    // layout: [A0 32K | A1 32K | B0 32K | B1 32K]
    const int K = 768;

    int bx, by, bz; xcd_remap(bx, by, bz);
    const int bm = bx * 256;
    const int bn = by * 256;
    const long long z = bz;

    const ushort* BHb = BH + z * sB;
    const ushort* BLb = BL + z * sB;

    const int t    = threadIdx.x;
    const int lane = t & 63;
    const int w    = t >> 6;
    const int wr   = w >> 2;        // 0..1
    const int wc   = w & 3;         // 0..3
    const int lrow = lane & 15;
    const int kg16 = (lane >> 4) * 16;

    // staging: 4 A-chunks + 4 B-chunks per thread. Physical slot p=lane&7 of
    // row holds logical slot q = p ^ (row&7); q<4 -> hi plane, else lo plane.
    const ushort* srcA[4]; const ushort* srcB[4]; int ldsO[4];
    #pragma unroll
    for (int i = 0; i < 4; ++i) {
        const int row  = w * 32 + i * 8 + (lane >> 3);
        const int q    = (lane & 7) ^ (row & 7);
        const int colo = (q & 3) * 8;
        srcA[i] = ((q < 4) ? AH : AL) + (long long)min(bm + row, M - 1) * K + colo;
        srcB[i] = ((q < 4) ? BHb : BLb) + (long long)(bn + row) * K + colo;
        ldsO[i] = w * 4096 + i * 1024;  // wave-uniform
    }

#define STAGE(k0_, cur_)                                                      \
    {                                                                         \
        _Pragma("unroll")                                                     \
        for (int i = 0; i < 4; ++i) {                                         \
            gload16(srcA[i] + (k0_), smem + (cur_) * 32768 + ldsO[i]);        \
            gload16(srcB[i] + (k0_), smem + 65536 + (cur_) * 32768 + ldsO[i]);\
        }                                                                     \
    }

    // prologue: tiles 0 and 1
    STAGE(0, 0);
    STAGE(32, 1);
    asm volatile("s_waitcnt vmcnt(8)" ::: "memory");
    __builtin_amdgcn_s_barrier();

    f32x4 acc[8][4] = {};

    for (int tt = 0; tt < 24; ++tt) {
        const int cur = tt & 1;
        const char* Ab = smem + cur * 32768;
        const char* Bb = smem + 65536 + cur * 32768;

        __builtin_amdgcn_s_setprio(1);
        short8 bh[4], bl[4];
        #pragma unroll
        for (int n = 0; n < 4; ++n) {
            bh[n] = *(const short8*)(Bb + swz(wc * 64 + n * 16 + lrow, kg16));
            bl[n] = *(const short8*)(Bb + swz(wc * 64 + n * 16 + lrow, 64 + kg16));
        }
        #pragma unroll
        for (int g = 0; g < 2; ++g) {
            short8 ah[4], al[4];
            #pragma unroll
            for (int m4 = 0; m4 < 4; ++m4) {
                const int r = wr * 128 + (g * 4 + m4) * 16 + lrow;
                ah[m4] = *(const short8*)(Ab + swz(r, kg16));
                al[m4] = *(const short8*)(Ab + swz(r, 64 + kg16));
            }
            #pragma unroll
            for (int m4 = 0; m4 < 4; ++m4)
                #pragma unroll
                for (int n = 0; n < 4; ++n) {
                    acc[g*4+m4][n] = __builtin_amdgcn_mfma_f32_16x16x32_bf16(
                        al[m4], bh[n], acc[g*4+m4][n], 0, 0, 0);
                    acc[g*4+m4][n] = __builtin_amdgcn_mfma_f32_16x16x32_bf16(
                        ah[m4], bl[n], acc[g*4+m4][n], 0, 0, 0);
                    acc[g*4+m4][n] = __builtin_amdgcn_mfma_f32_16x16x32_bf16(
                        ah[m4], bh[n], acc[g*4+m4][n], 0, 0, 0);
                }
        }
        __builtin_amdgcn_s_setprio(0);

        asm volatile("s_waitcnt lgkmcnt(0)" ::: "memory");
        __builtin_amdgcn_s_barrier();

        if (tt + 2 < 24) {
            STAGE((tt + 2) * 32, cur);
            asm volatile("s_waitcnt vmcnt(8)" ::: "memory");
        } else {
            asm volatile("s_waitcnt vmcnt(0)" ::: "memory");
        }
        __builtin_amdgcn_s_barrier();
    }
#undef STAGE

    // ---- C write ----
    float* C = Cb + z * sC;
    const int r0 = bm + wr * 128 + (lane >> 4) * 4;
    const int c0 = bn + wc * 64 + (lane & 15);
    #pragma unroll
    for (int n = 0; n < 4; ++n) {
        const int col = c0 + n * 16;
        #pragma unroll
        for (int mi = 0; mi < 8; ++mi) {
            #pragma unroll
            for (int r = 0; r < 4; ++r) {
                const int row = r0 + mi * 16 + r;
                if (row < M) C[(long long)row * N + col] = acc[mi][n][r];
            }
        }
    }

    // ---- fused per-column (max, sum) over the block's 256 rows ----
    __syncthreads();
    float* red = (float*)smem;                       // [256][8]
    const int slot = wr * 4 + (lane >> 4);
    const int colb = wc * 64 + (lane & 15);

    float lm[4];
    #pragma unroll
    for (int n = 0; n < 4; ++n) {
        float v = -INFINITY;
        #pragma unroll
        for (int mi = 0; mi < 8; ++mi)
            #pragma unroll
            for (int r = 0; r < 4; ++r)
                if (r0 + mi * 16 + r < M) v = fmaxf(v, acc[mi][n][r]);
        lm[n] = v;
    }
    #pragma unroll
    for (int n = 0; n < 4; ++n)
        red[(colb + n * 16) * 8 + slot] = lm[n];
    __syncthreads();
    float cm[4];
    #pragma unroll
    for (int n = 0; n < 4; ++n) {
        float v = -INFINITY;
        #pragma unroll
        for (int s8 = 0; s8 < 8; ++s8)
            v = fmaxf(v, red[(colb + n * 16) * 8 + s8]);
        cm[n] = v;
    }
    __syncthreads();
    float ls[4];
    #pragma unroll
    for (int n = 0; n < 4; ++n) {
        float sum = 0.f;
        #pragma unroll
        for (int mi = 0; mi < 8; ++mi)
            #pragma unroll
            for (int r = 0; r < 4; ++r)
                if (r0 + mi * 16 + r < M) sum += __expf(acc[mi][n][r] - cm[n]);
        ls[n] = sum;
    }
    #pragma unroll
    for (int n = 0; n < 4; ++n)
        red[(colb + n * 16) * 8 + slot] = ls[n];
    __syncthreads();
    if (slot == 0) {
        #pragma unroll
        for (int n = 0; n < 4; ++n) {
            float sum = 0.f;
            #pragma unroll
            for (int s8 = 0; s8 < 8; ++s8)
                sum += red[(colb + n * 16) * 8 + s8];
            const int col = bn + colb + n * 16;
            pmo[(z * SM_CH + bx) * N + col] = cm[n];
            pso[(z * SM_CH + bx) * N + col] = sum;
        }
    }
}

// ---------------------------------------------------------------------------
// attn GEMM v2: 4-wave, BM=128 x BN=128, BK=64, dbuf, counted vmcnt.
// 64 KB LDS -> 2 blocks/CU (vs 96KB/1 before): block-level overlap hides
// the barrier/vmcnt drains. Grid 1536 = 3 exact residency rounds, no tail.
// ---------------------------------------------------------------------------
template<int ROWS, int KS>
__device__ inline void stage_plane256(const ushort* __restrict__ src,
                                      char* plane, int t, int rbase, int rmax)
{
    #pragma unroll
    for (int s = 0; s < ROWS / 32; ++s) {
        const int row = s * 32 + (t >> 3);
        const int col = (((t & 7) * 16) ^ ((row & 7) << 4)) >> 1;  // elems
        const int gr  = min(rbase + row, rmax);
        gload16(src + (long long)gr * KS + col,
                plane + s * 4096 + (t >> 6) * 1024);
    }
}

__global__ __launch_bounds__(256, 2) void mfma_attn4(
    const ushort* __restrict__ A, const ushort* __restrict__ B,
    float* __restrict__ Cb, int M, int N,
    long long sA, long long sB, long long sC)
{
    extern __shared__ char smem[];
    // A0 16K | A1 16K | B0 16K | B1 16K
    constexpr int NT = 8, KS = 512;

    int bx, by, bz; xcd_remap(bx, by, bz);
    const int bm = bx * 128;
    const int bn = by * 128;
    const long long z = bz;

    const ushort* Ab_g = A + z * sA;
    const ushort* Bb_g = B + z * sB;

    const int t    = threadIdx.x;
    const int lane = t & 63;
    const int w    = t >> 6;        // 0..3
    const int wr   = w >> 1;        // 0..1
    const int wc   = w & 1;         // 0..1
    const int lrow = lane & 15;
    const int kg16 = (lane >> 4) * 16;

    stage_plane256<128, KS>(Ab_g, smem, t, bm, M - 1);
    stage_plane256<128, KS>(Bb_g, smem + 32768, t, bn, N - 1);
    stage_plane256<128, KS>(Ab_g + 64, smem + 16384, t, bm, M - 1);
    stage_plane256<128, KS>(Bb_g + 64, smem + 49152, t, bn, N - 1);
    asm volatile("s_waitcnt vmcnt(8)" ::: "memory");
    __builtin_amdgcn_s_barrier();

    f32x4 acc[4][4] = {};

    for (int tt = 0; tt < NT; ++tt) {
        const int cur = tt & 1;
        char* Ab = smem + cur * 16384;
        char* Bb = smem + 32768 + cur * 16384;

        __builtin_amdgcn_s_setprio(1);
        short8 bf[4][2];
        #pragma unroll
        for (int n = 0; n < 4; ++n)
            #pragma unroll
            for (int ks = 0; ks < 2; ++ks)
                bf[n][ks] = *(const short8*)(Bb + swz(wc * 64 + n * 16 + lrow,
                                                      ks * 64 + kg16));
        #pragma unroll
        for (int q = 0; q < 2; ++q) {
            short8 af[2][2];
            #pragma unroll
            for (int mi = 0; mi < 2; ++mi)
                #pragma unroll
                for (int ks = 0; ks < 2; ++ks)
                    af[mi][ks] = *(const short8*)(Ab +
                        swz(wr * 64 + (q * 2 + mi) * 16 + lrow, ks * 64 + kg16));
            #pragma unroll
            for (int ks = 0; ks < 2; ++ks)
                #pragma unroll
                for (int mi = 0; mi < 2; ++mi)
                    #pragma unroll
                    for (int n = 0; n < 4; ++n)
                        acc[q * 2 + mi][n] = __builtin_amdgcn_mfma_f32_16x16x32_bf16(
                            af[mi][ks], bf[n][ks], acc[q * 2 + mi][n], 0, 0, 0);
        }
        __builtin_amdgcn_s_setprio(0);

        asm volatile("s_waitcnt lgkmcnt(0)" ::: "memory");
        __builtin_amdgcn_s_barrier();

        if (tt + 2 < NT) {
            stage_plane256<128, KS>(Ab_g + (tt + 2) * 64, smem + cur * 16384,
                                    t, bm, M - 1);
            stage_plane256<128, KS>(Bb_g + (tt + 2) * 64,
                                    smem + 32768 + cur * 16384, t, bn, N - 1);
            asm volatile("s_waitcnt vmcnt(8)" ::: "memory");
        } else {
            asm volatile("s_waitcnt vmcnt(0)" ::: "memory");
        }
        __builtin_amdgcn_s_barrier();
    }

    float* C = Cb + z * sC;
    const int r0 = bm + wr * 64 + (lane >> 4) * 4;
    const int c0 = bn + wc * 64 + (lane & 15);
    #pragma unroll
    for (int n = 0; n < 4; ++n) {
        const int col = c0 + n * 16;
        #pragma unroll
        for (int mi = 0; mi < 4; ++mi) {
            #pragma unroll
            for (int r = 0; r < 4; ++r) {
                const int row = r0 + mi * 16 + r;
                if (row < M) C[(long long)row * N + col] = acc[mi][n][r];
            }
        }
    }
}

// ---------------------------------------------------------------------------
// split f32 array -> hi/lo bf16 planes (one-shot, for label)
// ---------------------------------------------------------------------------
__global__ __launch_bounds__(256) void split_planes_kernel(
    const float* __restrict__ in, ushort* __restrict__ H,
    ushort* __restrict__ L, long long n4)
{
    long long i = (long long)blockIdx.x * 256 + threadIdx.x;
    if (i >= n4) return;
    float4 v = *(const float4*)(in + i * 4);
    ushort h[4], l[4];
    split2(v.x, h[0], l[0]); split2(v.y, h[1], l[1]);
    split2(v.z, h[2], l[2]); split2(v.w, h[3], l[3]);
    *(ushort4*)(H + i * 4) = *(ushort4*)h;
    *(ushort4*)(L + i * 4) = *(ushort4*)l;
}

// ---------------------------------------------------------------------------
// proj GEMM (R6-proven): projH/projL = split2(tanh(lhs @ W^T + bias))
// ---------------------------------------------------------------------------
__global__ __launch_bounds__(256) void mfma_proj(
    const float* __restrict__ Ab, const float* __restrict__ Bb,
    ushort* __restrict__ CH, ushort* __restrict__ CL,
    const float* __restrict__ bias, int M, int N, int K)
{
    extern __shared__ char smem[];
    char* Ah = smem;
    char* Al = smem + 16384;
    char* Bh = smem + 32768;
    char* Bl = smem + 49152;

    int bx, by, bz; xcd_remap(bx, by, bz);
    const int bm = bx * 128;
    const int bn = by * 128;

    const int t  = threadIdx.x;
    const int srow = t >> 1;
    const int skh  = (t & 1) * 32;
    const float* ap = Ab + (long long)min(bm + srow, M - 1) * K + skh;
    const float* bp = Bb + (long long)min(bn + srow, N - 1) * K + skh;

    const int lane = t & 63;
    const int w    = t >> 6;
    const int wm   = (w >> 1) * 64;
    const int wn   = (w & 1) * 64;
    const int lrow = lane & 15;
    const int kg16 = (lane >> 4) * 16;

    f32x4 acc[4][4] = {};

    for (int k0 = 0; k0 < K; k0 += 64) {
        #pragma unroll
        for (int j = 0; j < 4; ++j) {
            float xs[8];
            *(float4*)&xs[0] = *(const float4*)(ap + k0 + j * 8);
            *(float4*)&xs[4] = *(const float4*)(ap + k0 + j * 8 + 4);
            ushort oh[8], ol[8];
            #pragma unroll
            for (int i = 0; i < 8; ++i) split2(xs[i], oh[i], ol[i]);
            const int off = swz(srow, skh * 2 + j * 16);
            *(uint4*)(Ah + off) = *(uint4*)oh;
            *(uint4*)(Al + off) = *(uint4*)ol;
        }
        #pragma unroll
        for (int j = 0; j < 4; ++j) {
            float xs[8];
            *(float4*)&xs[0] = *(const float4*)(bp + k0 + j * 8);
            *(float4*)&xs[4] = *(const float4*)(bp + k0 + j * 8 + 4);
            ushort oh[8], ol[8];
            #pragma unroll
            for (int i = 0; i < 8; ++i) split2(xs[i], oh[i], ol[i]);
            const int off = swz(srow, skh * 2 + j * 16);
            *(uint4*)(Bh + off) = *(uint4*)oh;
            *(uint4*)(Bl + off) = *(uint4*)ol;
        }
        __syncthreads();

        #pragma unroll
        for (int kk = 0; kk < 2; ++kk) {
            short8 ah[4], al[4];
            #pragma unroll
            for (int mi = 0; mi < 4; ++mi) {
                const int off = swz(wm + mi * 16 + lrow, kk * 64 + kg16);
                ah[mi] = *(const short8*)(Ah + off);
                al[mi] = *(const short8*)(Al + off);
            }
            #pragma unroll
            for (int ni = 0; ni < 4; ++ni) {
                const int off = swz(wn + ni * 16 + lrow, kk * 64 + kg16);
                short8 bh = *(const short8*)(Bh + off);
                short8 bl = *(const short8*)(Bl + off);
                #pragma unroll
                for (int mi = 0; mi < 4; ++mi) {
                    acc[mi][ni] = __builtin_amdgcn_mfma_f32_16x16x32_bf16(al[mi], bh, acc[mi][ni], 0, 0, 0);
                    acc[mi][ni] = __builtin_amdgcn_mfma_f32_16x16x32_bf16(ah[mi], bl, acc[mi][ni], 0, 0, 0);
                    acc[mi][ni] = __builtin_amdgcn_mfma_f32_16x16x32_bf16(ah[mi], bh, acc[mi][ni], 0, 0, 0);
                }
            }
        }
        __syncthreads();
    }

    const int r0 = bm + wm + (lane >> 4) * 4;
    const int c0 = bn + wn + (lane & 15);
    #pragma unroll
    for (int ni = 0; ni < 4; ++ni) {
        const int col = c0 + ni * 16;
        const float bv = bias[col];
        #pragma unroll
        for (int mi = 0; mi < 4; ++mi) {
            #pragma unroll
            for (int r = 0; r < 4; ++r) {
                const int row = r0 + mi * 16 + r;
                if (row < M) {
                    float x = tanhf(acc[mi][ni][r] + bv);
                    ushort h, l;
                    split2(x, h, l);
                    CH[(long long)row * N + col] = h;
                    CL[(long long)row * N + col] = l;
                }
            }
        }
    }
}

// ---------------------------------------------------------------------------
// lhs [B,S,D] f32  ->  lhsT [B,D,S] bf16
// ---------------------------------------------------------------------------
__global__ __launch_bounds__(256) void transpose_bf16_kernel(
    const float* __restrict__ in, ushort* __restrict__ out, int S, int D)
{
    __shared__ float tile[32][33];
    const int b = blockIdx.z;
    const int s0 = blockIdx.x * 32, d0 = blockIdx.y * 32;
    const int tx = threadIdx.x & 31, ty = threadIdx.x >> 5;
    const float* ip = in + (long long)b * S * D;
    #pragma unroll
    for (int i = 0; i < 32; i += 8)
        tile[ty + i][tx] = ip[(long long)(s0 + ty + i) * D + d0 + tx];
    __syncthreads();
    ushort* op = out + (long long)b * S * D;
    #pragma unroll
    for (int i = 0; i < 32; i += 8)
        op[(long long)(d0 + ty + i) * S + s0 + tx] = f2bf(tile[tx][ty + i]);
}

// ---------------------------------------------------------------------------
// Softmax write with inlined merge (reads chunk stats pm/ps directly).
// ---------------------------------------------------------------------------
__global__ __launch_bounds__(256) void softmax_write2_kernel(
    float* __restrict__ scores, const float* __restrict__ pm,
    const float* __restrict__ ps, int L, int S, int chlen,
    ushort* __restrict__ wbf)
{
    int s = blockIdx.x * 256 + threadIdx.x;
    int c = blockIdx.y;
    int b = blockIdx.z;

    float m = -INFINITY;
    #pragma unroll
    for (int k = 0; k < SM_CH; ++k)
        m = fmaxf(m, pm[(b * SM_CH + k) * S + s]);
    float sum = 0.f;
    #pragma unroll
    for (int k = 0; k < SM_CH; ++k)
        sum += ps[(b * SM_CH + k) * S + s] * __expf(pm[(b * SM_CH + k) * S + s] - m);
    float inv = 1.f / sum;

    float* p = scores + (long long)b * L * S + s;
    ushort* q = wbf + (long long)b * L * S + s;
    int l0 = c * chlen;
    int l1 = min(L, l0 + chlen);
    for (int l = l0; l < l1; ++l) {
        float x = p[(long long)l * S];
        float v = __expf(x - m) * inv;
        p[(long long)l * S] = v;
        q[(long long)l * S] = f2bf(v);
    }
}

extern "C" void kernel_launch(void* const* d_in, const int* in_sizes, int n_in,
                              void* d_out, int out_size, void* d_ws, size_t ws_size,
                              hipStream_t stream)
{
    const int Bn = 8, S = 512, D = 768, E = 768, L = 4000;
    const float* lhs   = (const float*)d_in[0];   // [B,S,D]
    const float* label = (const float*)d_in[1];   // [L,E]
    const float* W     = (const float*)d_in[2];   // [E,D]
    const float* bias  = (const float*)d_in[3];   // [E]

    float* weights = (float*)d_out;                          // [B,L,S]
    float* attn    = (float*)d_out + (long long)Bn * L * S;  // [B,L,D]

    const long long nLE  = (long long)L * E;        // 3,072,000
    const long long nBSE = (long long)Bn * S * E;   // 3,145,728
    const long long nBDS = (long long)Bn * D * S;   // 3,145,728
    const long long nBLS = (long long)Bn * L * S;   // 16,384,000

    ushort* labelH = (ushort*)d_ws;
    ushort* labelL = labelH + nLE;
    ushort* projH  = labelL + nLE;
    ushort* projL  = projH + nBSE;
    ushort* lhsT   = projL + nBSE;
    ushort* wbf    = lhsT + nBDS;
    float*  pm     = (float*)(wbf + nBLS);
    float*  ps     = pm + Bn * SM_CH * S;

    hipFuncSetAttribute((const void*)mfma_sc2,
                        hipFuncAttributeMaxDynamicSharedMemorySize, 131072);
    hipFuncSetAttribute((const void*)mfma_attn4,
                        hipFuncAttributeMaxDynamicSharedMemorySize, 65536);

    // 0) lhsT (bf16 transpose) + label hi/lo planes
    transpose_bf16_kernel<<<dim3(S / 32, D / 32, Bn), 256, 0, stream>>>(
        lhs, lhsT, S, D);
    split_planes_kernel<<<(int)(nLE / 4 + 255) / 256, 256, 0, stream>>>(
        label, labelH, labelL, nLE / 4);

    // 1) projH/L = split(tanh(lhs @ W^T + bias))
    mfma_proj<<<dim3((Bn * S) / 128, E / 128, 1), 256, 65536, stream>>>(
        lhs, W, projH, projL, bias, Bn * S, E, D);

    // 2) scores + fused per-chunk (max,sum): M=L, N=S, K=768, BK=32
    mfma_sc2<<<dim3((L + 255) / 256, S / 256, Bn), 512, 131072, stream>>>(
        labelH, labelL, projH, projL, weights, pm, ps,
        L, S, (long long)S * E, (long long)L * S);

    // 3) softmax write with inlined merge (in place, + bf16 copy)
    softmax_write2_kernel<<<dim3(S / 256, WCH, Bn), 256, 0, stream>>>(
        weights, pm, ps, L, S, (L + WCH - 1) / WCH, wbf);

    // 4) attn = wbf @ lhsT^T: M=L, N=D, K=512  (128x128, 2 blocks/CU)
    mfma_attn4<<<dim3((L + 127) / 128, D / 128, Bn), 256, 65536, stream>>>(
        wbf, lhsT, attn, L, D,
        (long long)L * S, (long long)D * S, (long long)L * D);
}

// Round 13
// 242.427 us; speedup vs baseline: 1.0414x; 1.0414x over previous
//
#include <hip/hip_runtime.h>
#include <hip/hip_bf16.h>
#include <cmath>

typedef __attribute__((ext_vector_type(8))) short short8;
typedef __attribute__((ext_vector_type(4))) float f32x4;

#define SM_CH 16   // scores stats chunks: 4000 rows / 256-row blocks -> 16
#define WCH   32   // softmax write-pass chunking

__device__ inline ushort f2bf(float x) {
    union { float f; unsigned u; } v; v.f = x;
    unsigned r = v.u + 0x7FFF + ((v.u >> 16) & 1);   // RNE
    return (ushort)(r >> 16);
}

__device__ inline void split2(float x, ushort& hi, ushort& lo) {
    union { float f; unsigned u; } v; v.f = x;
    hi = (ushort)(v.u >> 16);
    union { float f; unsigned u; } h; h.u = v.u & 0xFFFF0000u;
    union { float f; unsigned u; } d; d.f = x - h.f;
    lo = (ushort)(d.u >> 16);
}

// byte offset within one [rows x 128B] LDS plane, XOR-swizzled (T2).
__device__ inline int swz(int row, int byte_in_row) {
    return row * 128 + (byte_in_row ^ ((row & 7) << 4));
}

// async global->LDS, 16B/lane; lds base wave-uniform, HW adds lane*16.
__device__ inline void gload16(const void* g, void* lds) {
    __builtin_amdgcn_global_load_lds(
        (const __attribute__((address_space(1))) unsigned int*)g,
        (__attribute__((address_space(3))) unsigned int*)lds, 16, 0, 0);
}

// T1: bijective XCD-aware block remap (requires nwg % 8 == 0).
__device__ inline void xcd_remap(int& bx, int& by, int& bz) {
    unsigned nx = gridDim.x, ny = gridDim.y;
    unsigned nwg = nx * ny * gridDim.z;
    unsigned id = blockIdx.x + nx * (blockIdx.y + ny * blockIdx.z);
    unsigned q = nwg >> 3;
    unsigned s = (id & 7) * q + (id >> 3);
    bx = s % nx; unsigned r = s / nx;
    by = r % ny; bz = r / ny;
}

// ---------------------------------------------------------------------------
// scores GEMM v2 (R9-proven): weights[b] = labelHL @ projHL[b]^T, 3-term split.
// BK=32, paired-plane LDS rows: [hi 32k | lo 32k] = 128B. All 4 planes
// staged ONCE per K-tile (64KB, dbuf in 128KB LDS); 24 ds_read feed 96 MFMA.
// Fused per-column (max,sum) partials over the block's 256 rows.
// ---------------------------------------------------------------------------
__global__ __launch_bounds__(512, 2) void mfma_sc2(
    const ushort* __restrict__ AH, const ushort* __restrict__ AL,
    const ushort* __restrict__ BH, const ushort* __restrict__ BL,
    float* __restrict__ Cb, float* __restrict__ pmo, float* __restrict__ pso,
    int M, int N, long long sB, long long sC)
{
    extern __shared__ char smem[];
    // layout: [A0 32K | A1 32K | B0 32K | B1 32K]
    const int K = 768;

    int bx, by, bz; xcd_remap(bx, by, bz);
    const int bm = bx * 256;
    const int bn = by * 256;
    const long long z = bz;

    const ushort* BHb = BH + z * sB;
    const ushort* BLb = BL + z * sB;

    const int t    = threadIdx.x;
    const int lane = t & 63;
    const int w    = t >> 6;
    const int wr   = w >> 2;        // 0..1
    const int wc   = w & 3;         // 0..3
    const int lrow = lane & 15;
    const int kg16 = (lane >> 4) * 16;

    // staging: 4 A-chunks + 4 B-chunks per thread. Physical slot p=lane&7 of
    // row holds logical slot q = p ^ (row&7); q<4 -> hi plane, else lo plane.
    const ushort* srcA[4]; const ushort* srcB[4]; int ldsO[4];
    #pragma unroll
    for (int i = 0; i < 4; ++i) {
        const int row  = w * 32 + i * 8 + (lane >> 3);
        const int q    = (lane & 7) ^ (row & 7);
        const int colo = (q & 3) * 8;
        srcA[i] = ((q < 4) ? AH : AL) + (long long)min(bm + row, M - 1) * K + colo;
        srcB[i] = ((q < 4) ? BHb : BLb) + (long long)(bn + row) * K + colo;
        ldsO[i] = w * 4096 + i * 1024;  // wave-uniform
    }

#define STAGE(k0_, cur_)                                                      \
    {                                                                         \
        _Pragma("unroll")                                                     \
        for (int i = 0; i < 4; ++i) {                                         \
            gload16(srcA[i] + (k0_), smem + (cur_) * 32768 + ldsO[i]);        \
            gload16(srcB[i] + (k0_), smem + 65536 + (cur_) * 32768 + ldsO[i]);\
        }                                                                     \
    }

    // prologue: tiles 0 and 1
    STAGE(0, 0);
    STAGE(32, 1);
    asm volatile("s_waitcnt vmcnt(8)" ::: "memory");
    __builtin_amdgcn_s_barrier();

    f32x4 acc[8][4] = {};

    for (int tt = 0; tt < 24; ++tt) {
        const int cur = tt & 1;
        const char* Ab = smem + cur * 32768;
        const char* Bb = smem + 65536 + cur * 32768;

        __builtin_amdgcn_s_setprio(1);
        short8 bh[4], bl[4];
        #pragma unroll
        for (int n = 0; n < 4; ++n) {
            bh[n] = *(const short8*)(Bb + swz(wc * 64 + n * 16 + lrow, kg16));
            bl[n] = *(const short8*)(Bb + swz(wc * 64 + n * 16 + lrow, 64 + kg16));
        }
        #pragma unroll
        for (int g = 0; g < 2; ++g) {
            short8 ah[4], al[4];
            #pragma unroll
            for (int m4 = 0; m4 < 4; ++m4) {
                const int r = wr * 128 + (g * 4 + m4) * 16 + lrow;
                ah[m4] = *(const short8*)(Ab + swz(r, kg16));
                al[m4] = *(const short8*)(Ab + swz(r, 64 + kg16));
            }
            #pragma unroll
            for (int m4 = 0; m4 < 4; ++m4)
                #pragma unroll
                for (int n = 0; n < 4; ++n) {
                    acc[g*4+m4][n] = __builtin_amdgcn_mfma_f32_16x16x32_bf16(
                        al[m4], bh[n], acc[g*4+m4][n], 0, 0, 0);
                    acc[g*4+m4][n] = __builtin_amdgcn_mfma_f32_16x16x32_bf16(
                        ah[m4], bl[n], acc[g*4+m4][n], 0, 0, 0);
                    acc[g*4+m4][n] = __builtin_amdgcn_mfma_f32_16x16x32_bf16(
                        ah[m4], bh[n], acc[g*4+m4][n], 0, 0, 0);
                }
        }
        __builtin_amdgcn_s_setprio(0);

        asm volatile("s_waitcnt lgkmcnt(0)" ::: "memory");
        __builtin_amdgcn_s_barrier();

        if (tt + 2 < 24) {
            STAGE((tt + 2) * 32, cur);
            asm volatile("s_waitcnt vmcnt(8)" ::: "memory");
        } else {
            asm volatile("s_waitcnt vmcnt(0)" ::: "memory");
        }
        __builtin_amdgcn_s_barrier();
    }
#undef STAGE

    // ---- C write ----
    float* C = Cb + z * sC;
    const int r0 = bm + wr * 128 + (lane >> 4) * 4;
    const int c0 = bn + wc * 64 + (lane & 15);
    #pragma unroll
    for (int n = 0; n < 4; ++n) {
        const int col = c0 + n * 16;
        #pragma unroll
        for (int mi = 0; mi < 8; ++mi) {
            #pragma unroll
            for (int r = 0; r < 4; ++r) {
                const int row = r0 + mi * 16 + r;
                if (row < M) C[(long long)row * N + col] = acc[mi][n][r];
            }
        }
    }

    // ---- fused per-column (max, sum) over the block's 256 rows ----
    __syncthreads();
    float* red = (float*)smem;                       // [256][8]
    const int slot = wr * 4 + (lane >> 4);
    const int colb = wc * 64 + (lane & 15);

    float lm[4];
    #pragma unroll
    for (int n = 0; n < 4; ++n) {
        float v = -INFINITY;
        #pragma unroll
        for (int mi = 0; mi < 8; ++mi)
            #pragma unroll
            for (int r = 0; r < 4; ++r)
                if (r0 + mi * 16 + r < M) v = fmaxf(v, acc[mi][n][r]);
        lm[n] = v;
    }
    #pragma unroll
    for (int n = 0; n < 4; ++n)
        red[(colb + n * 16) * 8 + slot] = lm[n];
    __syncthreads();
    float cm[4];
    #pragma unroll
    for (int n = 0; n < 4; ++n) {
        float v = -INFINITY;
        #pragma unroll
        for (int s8 = 0; s8 < 8; ++s8)
            v = fmaxf(v, red[(colb + n * 16) * 8 + s8]);
        cm[n] = v;
    }
    __syncthreads();
    float ls[4];
    #pragma unroll
    for (int n = 0; n < 4; ++n) {
        float sum = 0.f;
        #pragma unroll
        for (int mi = 0; mi < 8; ++mi)
            #pragma unroll
            for (int r = 0; r < 4; ++r)
                if (r0 + mi * 16 + r < M) sum += __expf(acc[mi][n][r] - cm[n]);
        ls[n] = sum;
    }
    #pragma unroll
    for (int n = 0; n < 4; ++n)
        red[(colb + n * 16) * 8 + slot] = ls[n];
    __syncthreads();
    if (slot == 0) {
        #pragma unroll
        for (int n = 0; n < 4; ++n) {
            float sum = 0.f;
            #pragma unroll
            for (int s8 = 0; s8 < 8; ++s8)
                sum += red[(colb + n * 16) * 8 + s8];
            const int col = bn + colb + n * 16;
            pmo[(z * SM_CH + bx) * N + col] = cm[n];
            pso[(z * SM_CH + bx) * N + col] = sum;
        }
    }
}

// ---------------------------------------------------------------------------
// attn GEMM (R8/R9/R11-proven): 8-wave, BM=128 x BN=256, BK=64, dbuf,
// counted vmcnt.
// ---------------------------------------------------------------------------
template<int ROWS, int KS>
__device__ inline void stage_plane(const ushort* __restrict__ src,
                                   char* plane, int t, int rbase, int rmax)
{
    #pragma unroll
    for (int s = 0; s < ROWS / 64; ++s) {
        const int row = s * 64 + (t >> 3);
        const int col = (((t & 7) * 16) ^ ((row & 7) << 4)) >> 1;  // elems
        const int gr  = min(rbase + row, rmax);
        gload16(src + (long long)gr * KS + col,
                plane + s * 8192 + (t >> 6) * 1024);
    }
}

__global__ __launch_bounds__(512, 2) void mfma_attn8(
    const ushort* __restrict__ A, const ushort* __restrict__ B,
    float* __restrict__ Cb, int M, int N,
    long long sA, long long sB, long long sC)
{
    extern __shared__ char smem[];
    constexpr int ABYTES = 128 * 128;   // one A buffer (BM=128)
    constexpr int NT = 8, KS = 512;

    int bx, by, bz; xcd_remap(bx, by, bz);
    const int bm = bx * 128;
    const int bn = by * 256;
    const long long z = bz;

    const ushort* Ab_g = A + z * sA;
    const ushort* Bb_g = B + z * sB;

    const int t    = threadIdx.x;
    const int lane = t & 63;
    const int w    = t >> 6;
    const int wr   = w >> 2;
    const int wc   = w & 3;
    const int lrow = lane & 15;
    const int kg16 = (lane >> 4) * 16;

    stage_plane<128, KS>(Ab_g, smem, t, bm, M - 1);
    stage_plane<256, KS>(Bb_g, smem + 2 * ABYTES, t, bn, N - 1);
    stage_plane<128, KS>(Ab_g + 64, smem + ABYTES, t, bm, M - 1);
    stage_plane<256, KS>(Bb_g + 64, smem + 2 * ABYTES + 32768, t, bn, N - 1);
    asm volatile("s_waitcnt vmcnt(6)" ::: "memory");
    __builtin_amdgcn_s_barrier();

    f32x4 acc[4][4] = {};

    for (int tt = 0; tt < NT; ++tt) {
        const int cur = tt & 1;
        char* Ab = smem + cur * ABYTES;
        char* Bb = smem + 2 * ABYTES + cur * 32768;

        __builtin_amdgcn_s_setprio(1);
        short8 bf[4][2];
        #pragma unroll
        for (int n = 0; n < 4; ++n)
            #pragma unroll
            for (int ks = 0; ks < 2; ++ks)
                bf[n][ks] = *(const short8*)(Bb + swz(wc * 64 + n * 16 + lrow,
                                                      ks * 64 + kg16));
        #pragma unroll
        for (int q = 0; q < 2; ++q) {
            short8 af[2][2];
            #pragma unroll
            for (int mi = 0; mi < 2; ++mi)
                #pragma unroll
                for (int ks = 0; ks < 2; ++ks)
                    af[mi][ks] = *(const short8*)(Ab +
                        swz(wr * 64 + (q * 2 + mi) * 16 + lrow, ks * 64 + kg16));
            #pragma unroll
            for (int ks = 0; ks < 2; ++ks)
                #pragma unroll
                for (int mi = 0; mi < 2; ++mi)
                    #pragma unroll
                    for (int n = 0; n < 4; ++n)
                        acc[q * 2 + mi][n] = __builtin_amdgcn_mfma_f32_16x16x32_bf16(
                            af[mi][ks], bf[n][ks], acc[q * 2 + mi][n], 0, 0, 0);
        }
        __builtin_amdgcn_s_setprio(0);

        asm volatile("s_waitcnt lgkmcnt(0)" ::: "memory");
        __builtin_amdgcn_s_barrier();

        if (tt + 2 < NT) {
            stage_plane<128, KS>(Ab_g + (tt + 2) * 64, smem + cur * ABYTES,
                                 t, bm, M - 1);
            stage_plane<256, KS>(Bb_g + (tt + 2) * 64,
                                 smem + 2 * ABYTES + cur * 32768, t, bn, N - 1);
            asm volatile("s_waitcnt vmcnt(6)" ::: "memory");
        } else {
            asm volatile("s_waitcnt vmcnt(0)" ::: "memory");
        }
        __builtin_amdgcn_s_barrier();
    }

    float* C = Cb + z * sC;
    const int r0 = bm + wr * 64 + (lane >> 4) * 4;
    const int c0 = bn + wc * 64 + (lane & 15);
    #pragma unroll
    for (int n = 0; n < 4; ++n) {
        const int col = c0 + n * 16;
        #pragma unroll
        for (int mi = 0; mi < 4; ++mi) {
            #pragma unroll
            for (int r = 0; r < 4; ++r) {
                const int row = r0 + mi * 16 + r;
                if (row < M) C[(long long)row * N + col] = acc[mi][n][r];
            }
        }
    }
}

// ---------------------------------------------------------------------------
// split f32 array -> hi/lo bf16 planes (one-shot, for label)
// ---------------------------------------------------------------------------
__global__ __launch_bounds__(256) void split_planes_kernel(
    const float* __restrict__ in, ushort* __restrict__ H,
    ushort* __restrict__ L, long long n4)
{
    long long i = (long long)blockIdx.x * 256 + threadIdx.x;
    if (i >= n4) return;
    float4 v = *(const float4*)(in + i * 4);
    ushort h[4], l[4];
    split2(v.x, h[0], l[0]); split2(v.y, h[1], l[1]);
    split2(v.z, h[2], l[2]); split2(v.w, h[3], l[3]);
    *(ushort4*)(H + i * 4) = *(ushort4*)h;
    *(ushort4*)(L + i * 4) = *(ushort4*)l;
}

// ---------------------------------------------------------------------------
// proj GEMM (R6-proven): projH/projL = split2(tanh(lhs @ W^T + bias))
// ---------------------------------------------------------------------------
__global__ __launch_bounds__(256) void mfma_proj(
    const float* __restrict__ Ab, const float* __restrict__ Bb,
    ushort* __restrict__ CH, ushort* __restrict__ CL,
    const float* __restrict__ bias, int M, int N, int K)
{
    extern __shared__ char smem[];
    char* Ah = smem;
    char* Al = smem + 16384;
    char* Bh = smem + 32768;
    char* Bl = smem + 49152;

    int bx, by, bz; xcd_remap(bx, by, bz);
    const int bm = bx * 128;
    const int bn = by * 128;

    const int t  = threadIdx.x;
    const int srow = t >> 1;
    const int skh  = (t & 1) * 32;
    const float* ap = Ab + (long long)min(bm + srow, M - 1) * K + skh;
    const float* bp = Bb + (long long)min(bn + srow, N - 1) * K + skh;

    const int lane = t & 63;
    const int w    = t >> 6;
    const int wm   = (w >> 1) * 64;
    const int wn   = (w & 1) * 64;
    const int lrow = lane & 15;
    const int kg16 = (lane >> 4) * 16;

    f32x4 acc[4][4] = {};

    for (int k0 = 0; k0 < K; k0 += 64) {
        #pragma unroll
        for (int j = 0; j < 4; ++j) {
            float xs[8];
            *(float4*)&xs[0] = *(const float4*)(ap + k0 + j * 8);
            *(float4*)&xs[4] = *(const float4*)(ap + k0 + j * 8 + 4);
            ushort oh[8], ol[8];
            #pragma unroll
            for (int i = 0; i < 8; ++i) split2(xs[i], oh[i], ol[i]);
            const int off = swz(srow, skh * 2 + j * 16);
            *(uint4*)(Ah + off) = *(uint4*)oh;
            *(uint4*)(Al + off) = *(uint4*)ol;
        }
        #pragma unroll
        for (int j = 0; j < 4; ++j) {
            float xs[8];
            *(float4*)&xs[0] = *(const float4*)(bp + k0 + j * 8);
            *(float4*)&xs[4] = *(const float4*)(bp + k0 + j * 8 + 4);
            ushort oh[8], ol[8];
            #pragma unroll
            for (int i = 0; i < 8; ++i) split2(xs[i], oh[i], ol[i]);
            const int off = swz(srow, skh * 2 + j * 16);
            *(uint4*)(Bh + off) = *(uint4*)oh;
            *(uint4*)(Bl + off) = *(uint4*)ol;
        }
        __syncthreads();

        #pragma unroll
        for (int kk = 0; kk < 2; ++kk) {
            short8 ah[4], al[4];
            #pragma unroll
            for (int mi = 0; mi < 4; ++mi) {
                const int off = swz(wm + mi * 16 + lrow, kk * 64 + kg16);
                ah[mi] = *(const short8*)(Ah + off);
                al[mi] = *(const short8*)(Al + off);
            }
            #pragma unroll
            for (int ni = 0; ni < 4; ++ni) {
                const int off = swz(wn + ni * 16 + lrow, kk * 64 + kg16);
                short8 bh = *(const short8*)(Bh + off);
                short8 bl = *(const short8*)(Bl + off);
                #pragma unroll
                for (int mi = 0; mi < 4; ++mi) {
                    acc[mi][ni] = __builtin_amdgcn_mfma_f32_16x16x32_bf16(al[mi], bh, acc[mi][ni], 0, 0, 0);
                    acc[mi][ni] = __builtin_amdgcn_mfma_f32_16x16x32_bf16(ah[mi], bl, acc[mi][ni], 0, 0, 0);
                    acc[mi][ni] = __builtin_amdgcn_mfma_f32_16x16x32_bf16(ah[mi], bh, acc[mi][ni], 0, 0, 0);
                }
            }
        }
        __syncthreads();
    }

    const int r0 = bm + wm + (lane >> 4) * 4;
    const int c0 = bn + wn + (lane & 15);
    #pragma unroll
    for (int ni = 0; ni < 4; ++ni) {
        const int col = c0 + ni * 16;
        const float bv = bias[col];
        #pragma unroll
        for (int mi = 0; mi < 4; ++mi) {
            #pragma unroll
            for (int r = 0; r < 4; ++r) {
                const int row = r0 + mi * 16 + r;
                if (row < M) {
                    float x = tanhf(acc[mi][ni][r] + bv);
                    ushort h, l;
                    split2(x, h, l);
                    CH[(long long)row * N + col] = h;
                    CL[(long long)row * N + col] = l;
                }
            }
        }
    }
}

// ---------------------------------------------------------------------------
// lhs [B,S,D] f32  ->  lhsT [B,D,S] bf16
// ---------------------------------------------------------------------------
__global__ __launch_bounds__(256) void transpose_bf16_kernel(
    const float* __restrict__ in, ushort* __restrict__ out, int S, int D)
{
    __shared__ float tile[32][33];
    const int b = blockIdx.z;
    const int s0 = blockIdx.x * 32, d0 = blockIdx.y * 32;
    const int tx = threadIdx.x & 31, ty = threadIdx.x >> 5;
    const float* ip = in + (long long)b * S * D;
    #pragma unroll
    for (int i = 0; i < 32; i += 8)
        tile[ty + i][tx] = ip[(long long)(s0 + ty + i) * D + d0 + tx];
    __syncthreads();
    ushort* op = out + (long long)b * S * D;
    #pragma unroll
    for (int i = 0; i < 32; i += 8)
        op[(long long)(d0 + ty + i) * S + s0 + tx] = f2bf(tile[tx][ty + i]);
}

// ---------------------------------------------------------------------------
// Softmax write with inlined merge (reads chunk stats pm/ps directly).
// ---------------------------------------------------------------------------
__global__ __launch_bounds__(256) void softmax_write2_kernel(
    float* __restrict__ scores, const float* __restrict__ pm,
    const float* __restrict__ ps, int L, int S, int chlen,
    ushort* __restrict__ wbf)
{
    int s = blockIdx.x * 256 + threadIdx.x;
    int c = blockIdx.y;
    int b = blockIdx.z;

    float m = -INFINITY;
    #pragma unroll
    for (int k = 0; k < SM_CH; ++k)
        m = fmaxf(m, pm[(b * SM_CH + k) * S + s]);
    float sum = 0.f;
    #pragma unroll
    for (int k = 0; k < SM_CH; ++k)
        sum += ps[(b * SM_CH + k) * S + s] * __expf(pm[(b * SM_CH + k) * S + s] - m);
    float inv = 1.f / sum;

    float* p = scores + (long long)b * L * S + s;
    ushort* q = wbf + (long long)b * L * S + s;
    int l0 = c * chlen;
    int l1 = min(L, l0 + chlen);
    for (int l = l0; l < l1; ++l) {
        float x = p[(long long)l * S];
        float v = __expf(x - m) * inv;
        p[(long long)l * S] = v;
        q[(long long)l * S] = f2bf(v);
    }
}

extern "C" void kernel_launch(void* const* d_in, const int* in_sizes, int n_in,
                              void* d_out, int out_size, void* d_ws, size_t ws_size,
                              hipStream_t stream)
{
    const int Bn = 8, S = 512, D = 768, E = 768, L = 4000;
    const float* lhs   = (const float*)d_in[0];   // [B,S,D]
    const float* label = (const float*)d_in[1];   // [L,E]
    const float* W     = (const float*)d_in[2];   // [E,D]
    const float* bias  = (const float*)d_in[3];   // [E]

    float* weights = (float*)d_out;                          // [B,L,S]
    float* attn    = (float*)d_out + (long long)Bn * L * S;  // [B,L,D]

    const long long nLE  = (long long)L * E;        // 3,072,000
    const long long nBSE = (long long)Bn * S * E;   // 3,145,728
    const long long nBDS = (long long)Bn * D * S;   // 3,145,728
    const long long nBLS = (long long)Bn * L * S;   // 16,384,000

    ushort* labelH = (ushort*)d_ws;
    ushort* labelL = labelH + nLE;
    ushort* projH  = labelL + nLE;
    ushort* projL  = projH + nBSE;
    ushort* lhsT   = projL + nBSE;
    ushort* wbf    = lhsT + nBDS;
    float*  pm     = (float*)(wbf + nBLS);
    float*  ps     = pm + Bn * SM_CH * S;

    hipFuncSetAttribute((const void*)mfma_sc2,
                        hipFuncAttributeMaxDynamicSharedMemorySize, 131072);
    hipFuncSetAttribute((const void*)mfma_attn8,
                        hipFuncAttributeMaxDynamicSharedMemorySize, 98304);

    // 0) lhsT (bf16 transpose) + label hi/lo planes
    transpose_bf16_kernel<<<dim3(S / 32, D / 32, Bn), 256, 0, stream>>>(
        lhs, lhsT, S, D);
    split_planes_kernel<<<(int)(nLE / 4 + 255) / 256, 256, 0, stream>>>(
        label, labelH, labelL, nLE / 4);

    // 1) projH/L = split(tanh(lhs @ W^T + bias))
    mfma_proj<<<dim3((Bn * S) / 128, E / 128, 1), 256, 65536, stream>>>(
        lhs, W, projH, projL, bias, Bn * S, E, D);

    // 2) scores + fused per-chunk (max,sum): M=L, N=S, K=768, BK=32
    mfma_sc2<<<dim3((L + 255) / 256, S / 256, Bn), 512, 131072, stream>>>(
        labelH, labelL, projH, projL, weights, pm, ps,
        L, S, (long long)S * E, (long long)L * S);

    // 3) softmax write with inlined merge (in place, + bf16 copy)
    softmax_write2_kernel<<<dim3(S / 256, WCH, Bn), 256, 0, stream>>>(
        weights, pm, ps, L, S, (L + WCH - 1) / WCH, wbf);

    // 4) attn = wbf @ lhsT^T: M=L, N=D, K=512
    mfma_attn8<<<dim3((L + 127) / 128, D / 256, Bn), 512, 98304, stream>>>(
        wbf, lhsT, attn, L, D,
        (long long)L * S, (long long)D * S, (long long)L * D);
}

// Round 14
// 238.734 us; speedup vs baseline: 1.0575x; 1.0155x over previous
//
#include <hip/hip_runtime.h>
#include <hip/hip_bf16.h>
#include <cmath>

typedef __attribute__((ext_vector_type(8))) short short8;
typedef __attribute__((ext_vector_type(4))) float f32x4;

#define SM_CH 16   // scores stats chunks: 4000 rows / 256-row blocks -> 16
#define WCH   32   // softmax write-pass chunking

__device__ inline ushort f2bf(float x) {
    union { float f; unsigned u; } v; v.f = x;
    unsigned r = v.u + 0x7FFF + ((v.u >> 16) & 1);   // RNE
    return (ushort)(r >> 16);
}

__device__ inline void split2(float x, ushort& hi, ushort& lo) {
    union { float f; unsigned u; } v; v.f = x;
    hi = (ushort)(v.u >> 16);
    union { float f; unsigned u; } h; h.u = v.u & 0xFFFF0000u;
    union { float f; unsigned u; } d; d.f = x - h.f;
    lo = (ushort)(d.u >> 16);
}

// byte offset within one [rows x 128B] LDS plane, XOR-swizzled (T2).
__device__ inline int swz(int row, int byte_in_row) {
    return row * 128 + (byte_in_row ^ ((row & 7) << 4));
}

// async global->LDS, 16B/lane; lds base wave-uniform, HW adds lane*16.
__device__ inline void gload16(const void* g, void* lds) {
    __builtin_amdgcn_global_load_lds(
        (const __attribute__((address_space(1))) unsigned int*)g,
        (__attribute__((address_space(3))) unsigned int*)lds, 16, 0, 0);
}

// T1: bijective XCD-aware block remap (requires nwg % 8 == 0).
__device__ inline void xcd_remap(int& bx, int& by, int& bz) {
    unsigned nx = gridDim.x, ny = gridDim.y;
    unsigned nwg = nx * ny * gridDim.z;
    unsigned id = blockIdx.x + nx * (blockIdx.y + ny * blockIdx.z);
    unsigned q = nwg >> 3;
    unsigned s = (id & 7) * q + (id >> 3);
    bx = s % nx; unsigned r = s / nx;
    by = r % ny; bz = r / ny;
}

// ---------------------------------------------------------------------------
// scores GEMM v2 (R9-proven): weights[b] = labelHL @ projHL[b]^T, 3-term split.
// BK=32, paired-plane LDS rows: [hi 32k | lo 32k] = 128B. All 4 planes
// staged ONCE per K-tile (64KB, dbuf in 128KB LDS); 24 ds_read feed 96 MFMA.
// Fused per-column (max,sum) partials over the block's 256 rows.
// ---------------------------------------------------------------------------
__global__ __launch_bounds__(512, 2) void mfma_sc2(
    const ushort* __restrict__ AH, const ushort* __restrict__ AL,
    const ushort* __restrict__ BH, const ushort* __restrict__ BL,
    float* __restrict__ Cb, float* __restrict__ pmo, float* __restrict__ pso,
    int M, int N, long long sB, long long sC)
{
    extern __shared__ char smem[];
    // layout: [A0 32K | A1 32K | B0 32K | B1 32K]
    const int K = 768;

    int bx, by, bz; xcd_remap(bx, by, bz);
    const int bm = bx * 256;
    const int bn = by * 256;
    const long long z = bz;

    const ushort* BHb = BH + z * sB;
    const ushort* BLb = BL + z * sB;

    const int t    = threadIdx.x;
    const int lane = t & 63;
    const int w    = t >> 6;
    const int wr   = w >> 2;        // 0..1
    const int wc   = w & 3;         // 0..3
    const int lrow = lane & 15;
    const int kg16 = (lane >> 4) * 16;

    // staging: 4 A-chunks + 4 B-chunks per thread. Physical slot p=lane&7 of
    // row holds logical slot q = p ^ (row&7); q<4 -> hi plane, else lo plane.
    const ushort* srcA[4]; const ushort* srcB[4]; int ldsO[4];
    #pragma unroll
    for (int i = 0; i < 4; ++i) {
        const int row  = w * 32 + i * 8 + (lane >> 3);
        const int q    = (lane & 7) ^ (row & 7);
        const int colo = (q & 3) * 8;
        srcA[i] = ((q < 4) ? AH : AL) + (long long)min(bm + row, M - 1) * K + colo;
        srcB[i] = ((q < 4) ? BHb : BLb) + (long long)(bn + row) * K + colo;
        ldsO[i] = w * 4096 + i * 1024;  // wave-uniform
    }

#define STAGE(k0_, cur_)                                                      \
    {                                                                         \
        _Pragma("unroll")                                                     \
        for (int i = 0; i < 4; ++i) {                                         \
            gload16(srcA[i] + (k0_), smem + (cur_) * 32768 + ldsO[i]);        \
            gload16(srcB[i] + (k0_), smem + 65536 + (cur_) * 32768 + ldsO[i]);\
        }                                                                     \
    }

    // prologue: tiles 0 and 1
    STAGE(0, 0);
    STAGE(32, 1);
    asm volatile("s_waitcnt vmcnt(8)" ::: "memory");
    __builtin_amdgcn_s_barrier();

    f32x4 acc[8][4] = {};

    for (int tt = 0; tt < 24; ++tt) {
        const int cur = tt & 1;
        const char* Ab = smem + cur * 32768;
        const char* Bb = smem + 65536 + cur * 32768;

        __builtin_amdgcn_s_setprio(1);
        short8 bh[4], bl[4];
        #pragma unroll
        for (int n = 0; n < 4; ++n) {
            bh[n] = *(const short8*)(Bb + swz(wc * 64 + n * 16 + lrow, kg16));
            bl[n] = *(const short8*)(Bb + swz(wc * 64 + n * 16 + lrow, 64 + kg16));
        }
        #pragma unroll
        for (int g = 0; g < 2; ++g) {
            short8 ah[4], al[4];
            #pragma unroll
            for (int m4 = 0; m4 < 4; ++m4) {
                const int r = wr * 128 + (g * 4 + m4) * 16 + lrow;
                ah[m4] = *(const short8*)(Ab + swz(r, kg16));
                al[m4] = *(const short8*)(Ab + swz(r, 64 + kg16));
            }
            #pragma unroll
            for (int m4 = 0; m4 < 4; ++m4)
                #pragma unroll
                for (int n = 0; n < 4; ++n) {
                    acc[g*4+m4][n] = __builtin_amdgcn_mfma_f32_16x16x32_bf16(
                        al[m4], bh[n], acc[g*4+m4][n], 0, 0, 0);
                    acc[g*4+m4][n] = __builtin_amdgcn_mfma_f32_16x16x32_bf16(
                        ah[m4], bl[n], acc[g*4+m4][n], 0, 0, 0);
                    acc[g*4+m4][n] = __builtin_amdgcn_mfma_f32_16x16x32_bf16(
                        ah[m4], bh[n], acc[g*4+m4][n], 0, 0, 0);
                }
        }
        __builtin_amdgcn_s_setprio(0);

        asm volatile("s_waitcnt lgkmcnt(0)" ::: "memory");
        __builtin_amdgcn_s_barrier();

        if (tt + 2 < 24) {
            STAGE((tt + 2) * 32, cur);
            asm volatile("s_waitcnt vmcnt(8)" ::: "memory");
        } else {
            asm volatile("s_waitcnt vmcnt(0)" ::: "memory");
        }
        __builtin_amdgcn_s_barrier();
    }
#undef STAGE

    // ---- C write ----
    float* C = Cb + z * sC;
    const int r0 = bm + wr * 128 + (lane >> 4) * 4;
    const int c0 = bn + wc * 64 + (lane & 15);
    #pragma unroll
    for (int n = 0; n < 4; ++n) {
        const int col = c0 + n * 16;
        #pragma unroll
        for (int mi = 0; mi < 8; ++mi) {
            #pragma unroll
            for (int r = 0; r < 4; ++r) {
                const int row = r0 + mi * 16 + r;
                if (row < M) C[(long long)row * N + col] = acc[mi][n][r];
            }
        }
    }

    // ---- fused per-column (max, sum) over the block's 256 rows ----
    __syncthreads();
    float* red = (float*)smem;                       // [256][8]
    const int slot = wr * 4 + (lane >> 4);
    const int colb = wc * 64 + (lane & 15);

    float lm[4];
    #pragma unroll
    for (int n = 0; n < 4; ++n) {
        float v = -INFINITY;
        #pragma unroll
        for (int mi = 0; mi < 8; ++mi)
            #pragma unroll
            for (int r = 0; r < 4; ++r)
                if (r0 + mi * 16 + r < M) v = fmaxf(v, acc[mi][n][r]);
        lm[n] = v;
    }
    #pragma unroll
    for (int n = 0; n < 4; ++n)
        red[(colb + n * 16) * 8 + slot] = lm[n];
    __syncthreads();
    float cm[4];
    #pragma unroll
    for (int n = 0; n < 4; ++n) {
        float v = -INFINITY;
        #pragma unroll
        for (int s8 = 0; s8 < 8; ++s8)
            v = fmaxf(v, red[(colb + n * 16) * 8 + s8]);
        cm[n] = v;
    }
    __syncthreads();
    float ls[4];
    #pragma unroll
    for (int n = 0; n < 4; ++n) {
        float sum = 0.f;
        #pragma unroll
        for (int mi = 0; mi < 8; ++mi)
            #pragma unroll
            for (int r = 0; r < 4; ++r)
                if (r0 + mi * 16 + r < M) sum += __expf(acc[mi][n][r] - cm[n]);
        ls[n] = sum;
    }
    #pragma unroll
    for (int n = 0; n < 4; ++n)
        red[(colb + n * 16) * 8 + slot] = ls[n];
    __syncthreads();
    if (slot == 0) {
        #pragma unroll
        for (int n = 0; n < 4; ++n) {
            float sum = 0.f;
            #pragma unroll
            for (int s8 = 0; s8 < 8; ++s8)
                sum += red[(colb + n * 16) * 8 + s8];
            const int col = bn + colb + n * 16;
            pmo[(z * SM_CH + bx) * N + col] = cm[n];
            pso[(z * SM_CH + bx) * N + col] = sum;
        }
    }
}

// ---------------------------------------------------------------------------
// attn GEMM (R8/R9/R11-proven): 8-wave, BM=128 x BN=256, BK=64, dbuf,
// counted vmcnt.
// ---------------------------------------------------------------------------
template<int ROWS, int KS>
__device__ inline void stage_plane(const ushort* __restrict__ src,
                                   char* plane, int t, int rbase, int rmax)
{
    #pragma unroll
    for (int s = 0; s < ROWS / 64; ++s) {
        const int row = s * 64 + (t >> 3);
        const int col = (((t & 7) * 16) ^ ((row & 7) << 4)) >> 1;  // elems
        const int gr  = min(rbase + row, rmax);
        gload16(src + (long long)gr * KS + col,
                plane + s * 8192 + (t >> 6) * 1024);
    }
}

__global__ __launch_bounds__(512, 2) void mfma_attn8(
    const ushort* __restrict__ A, const ushort* __restrict__ B,
    float* __restrict__ Cb, int M, int N,
    long long sA, long long sB, long long sC)
{
    extern __shared__ char smem[];
    constexpr int ABYTES = 128 * 128;   // one A buffer (BM=128)
    constexpr int NT = 8, KS = 512;

    int bx, by, bz; xcd_remap(bx, by, bz);
    const int bm = bx * 128;
    const int bn = by * 256;
    const long long z = bz;

    const ushort* Ab_g = A + z * sA;
    const ushort* Bb_g = B + z * sB;

    const int t    = threadIdx.x;
    const int lane = t & 63;
    const int w    = t >> 6;
    const int wr   = w >> 2;
    const int wc   = w & 3;
    const int lrow = lane & 15;
    const int kg16 = (lane >> 4) * 16;

    stage_plane<128, KS>(Ab_g, smem, t, bm, M - 1);
    stage_plane<256, KS>(Bb_g, smem + 2 * ABYTES, t, bn, N - 1);
    stage_plane<128, KS>(Ab_g + 64, smem + ABYTES, t, bm, M - 1);
    stage_plane<256, KS>(Bb_g + 64, smem + 2 * ABYTES + 32768, t, bn, N - 1);
    asm volatile("s_waitcnt vmcnt(6)" ::: "memory");
    __builtin_amdgcn_s_barrier();

    f32x4 acc[4][4] = {};

    for (int tt = 0; tt < NT; ++tt) {
        const int cur = tt & 1;
        char* Ab = smem + cur * ABYTES;
        char* Bb = smem + 2 * ABYTES + cur * 32768;

        __builtin_amdgcn_s_setprio(1);
        short8 bf[4][2];
        #pragma unroll
        for (int n = 0; n < 4; ++n)
            #pragma unroll
            for (int ks = 0; ks < 2; ++ks)
                bf[n][ks] = *(const short8*)(Bb + swz(wc * 64 + n * 16 + lrow,
                                                      ks * 64 + kg16));
        #pragma unroll
        for (int q = 0; q < 2; ++q) {
            short8 af[2][2];
            #pragma unroll
            for (int mi = 0; mi < 2; ++mi)
                #pragma unroll
                for (int ks = 0; ks < 2; ++ks)
                    af[mi][ks] = *(const short8*)(Ab +
                        swz(wr * 64 + (q * 2 + mi) * 16 + lrow, ks * 64 + kg16));
            #pragma unroll
            for (int ks = 0; ks < 2; ++ks)
                #pragma unroll
                for (int mi = 0; mi < 2; ++mi)
                    #pragma unroll
                    for (int n = 0; n < 4; ++n)
                        acc[q * 2 + mi][n] = __builtin_amdgcn_mfma_f32_16x16x32_bf16(
                            af[mi][ks], bf[n][ks], acc[q * 2 + mi][n], 0, 0, 0);
        }
        __builtin_amdgcn_s_setprio(0);

        asm volatile("s_waitcnt lgkmcnt(0)" ::: "memory");
        __builtin_amdgcn_s_barrier();

        if (tt + 2 < NT) {
            stage_plane<128, KS>(Ab_g + (tt + 2) * 64, smem + cur * ABYTES,
                                 t, bm, M - 1);
            stage_plane<256, KS>(Bb_g + (tt + 2) * 64,
                                 smem + 2 * ABYTES + cur * 32768, t, bn, N - 1);
            asm volatile("s_waitcnt vmcnt(6)" ::: "memory");
        } else {
            asm volatile("s_waitcnt vmcnt(0)" ::: "memory");
        }
        __builtin_amdgcn_s_barrier();
    }

    float* C = Cb + z * sC;
    const int r0 = bm + wr * 64 + (lane >> 4) * 4;
    const int c0 = bn + wc * 64 + (lane & 15);
    #pragma unroll
    for (int n = 0; n < 4; ++n) {
        const int col = c0 + n * 16;
        #pragma unroll
        for (int mi = 0; mi < 4; ++mi) {
            #pragma unroll
            for (int r = 0; r < 4; ++r) {
                const int row = r0 + mi * 16 + r;
                if (row < M) C[(long long)row * N + col] = acc[mi][n][r];
            }
        }
    }
}

// ---------------------------------------------------------------------------
// split f32 array -> hi/lo bf16 planes (one-shot, for label and W)
// ---------------------------------------------------------------------------
__global__ __launch_bounds__(256) void split_planes_kernel(
    const float* __restrict__ in, ushort* __restrict__ H,
    ushort* __restrict__ L, long long n4)
{
    long long i = (long long)blockIdx.x * 256 + threadIdx.x;
    if (i >= n4) return;
    float4 v = *(const float4*)(in + i * 4);
    ushort h[4], l[4];
    split2(v.x, h[0], l[0]); split2(v.y, h[1], l[1]);
    split2(v.z, h[2], l[2]); split2(v.w, h[3], l[3]);
    *(ushort4*)(H + i * 4) = *(ushort4*)h;
    *(ushort4*)(L + i * 4) = *(ushort4*)l;
}

// ---------------------------------------------------------------------------
// proj GEMM v2 (= R4 mfma_scores structure, proven): A=lhs f32 reg-split,
// B = WH/WL bf16 planes via global_load_lds. tanh+split epilogue (R6-proven).
// LDS 64KB: Ah@0 Al@16K Bh@32K Bl@48K.
// ---------------------------------------------------------------------------
__global__ __launch_bounds__(256) void mfma_proj2(
    const float* __restrict__ Ab, const ushort* __restrict__ WH,
    const ushort* __restrict__ WL, ushort* __restrict__ CH,
    ushort* __restrict__ CL, const float* __restrict__ bias,
    int M, int N, int K)
{
    extern __shared__ char smem[];
    char* Ah = smem;
    char* Al = smem + 16384;
    char* Bh = smem + 32768;
    char* Bl = smem + 49152;

    int bx, by, bz; xcd_remap(bx, by, bz);
    const int bm = bx * 128;
    const int bn = by * 128;

    const int t    = threadIdx.x;
    const int lane = t & 63;
    const int w    = t >> 6;

    // A reg-staging (f32 -> hi/lo split in registers)
    const int srow = t >> 1;
    const int skh  = (t & 1) * 32;
    const float* ap = Ab + (long long)min(bm + srow, M - 1) * K + skh;

    // B gload: lane's fixed (row, col), inverse-swizzled source (R4-proven)
    const int lr  = lane >> 3;
    const int lc8 = 8 * ((lane & 7) ^ lr);
    const ushort* bh_src[4]; const ushort* bl_src[4];
    int ldsB[4];
    #pragma unroll
    for (int i = 0; i < 4; ++i) {
        const int row = w * 32 + i * 8 + lr;
        bh_src[i] = WH + (long long)(bn + row) * K + lc8;
        bl_src[i] = WL + (long long)(bn + row) * K + lc8;
        ldsB[i] = w * 4096 + i * 1024;
    }

    const int wm   = (w >> 1) * 64;
    const int wn   = (w & 1) * 64;
    const int lrow = lane & 15;
    const int kg16 = (lane >> 4) * 16;

    f32x4 acc[4][4] = {};

    for (int k0 = 0; k0 < K; k0 += 64) {
        #pragma unroll
        for (int i = 0; i < 4; ++i) {
            gload16(bh_src[i] + k0, Bh + ldsB[i]);
            gload16(bl_src[i] + k0, Bl + ldsB[i]);
        }
        #pragma unroll
        for (int j = 0; j < 4; ++j) {
            float xs[8];
            *(float4*)&xs[0] = *(const float4*)(ap + k0 + j * 8);
            *(float4*)&xs[4] = *(const float4*)(ap + k0 + j * 8 + 4);
            ushort oh[8], ol[8];
            #pragma unroll
            for (int i = 0; i < 8; ++i) split2(xs[i], oh[i], ol[i]);
            const int off = swz(srow, skh * 2 + j * 16);
            *(uint4*)(Ah + off) = *(uint4*)oh;
            *(uint4*)(Al + off) = *(uint4*)ol;
        }
        __syncthreads();

        #pragma unroll
        for (int kk = 0; kk < 2; ++kk) {
            short8 ah[4], al[4];
            #pragma unroll
            for (int mi = 0; mi < 4; ++mi) {
                const int off = swz(wm + mi * 16 + lrow, kk * 64 + kg16);
                ah[mi] = *(const short8*)(Ah + off);
                al[mi] = *(const short8*)(Al + off);
            }
            #pragma unroll
            for (int ni = 0; ni < 4; ++ni) {
                const int off = swz(wn + ni * 16 + lrow, kk * 64 + kg16);
                short8 bh = *(const short8*)(Bh + off);
                short8 bl = *(const short8*)(Bl + off);
                #pragma unroll
                for (int mi = 0; mi < 4; ++mi) {
                    acc[mi][ni] = __builtin_amdgcn_mfma_f32_16x16x32_bf16(al[mi], bh, acc[mi][ni], 0, 0, 0);
                    acc[mi][ni] = __builtin_amdgcn_mfma_f32_16x16x32_bf16(ah[mi], bl, acc[mi][ni], 0, 0, 0);
                    acc[mi][ni] = __builtin_amdgcn_mfma_f32_16x16x32_bf16(ah[mi], bh, acc[mi][ni], 0, 0, 0);
                }
            }
        }
        __syncthreads();
    }

    const int r0 = bm + wm + (lane >> 4) * 4;
    const int c0 = bn + wn + (lane & 15);
    #pragma unroll
    for (int ni = 0; ni < 4; ++ni) {
        const int col = c0 + ni * 16;
        const float bv = bias[col];
        #pragma unroll
        for (int mi = 0; mi < 4; ++mi) {
            #pragma unroll
            for (int r = 0; r < 4; ++r) {
                const int row = r0 + mi * 16 + r;
                if (row < M) {
                    float x = tanhf(acc[mi][ni][r] + bv);
                    ushort h, l;
                    split2(x, h, l);
                    CH[(long long)row * N + col] = h;
                    CL[(long long)row * N + col] = l;
                }
            }
        }
    }
}

// ---------------------------------------------------------------------------
// lhs [B,S,D] f32  ->  lhsT [B,D,S] bf16
// ---------------------------------------------------------------------------
__global__ __launch_bounds__(256) void transpose_bf16_kernel(
    const float* __restrict__ in, ushort* __restrict__ out, int S, int D)
{
    __shared__ float tile[32][33];
    const int b = blockIdx.z;
    const int s0 = blockIdx.x * 32, d0 = blockIdx.y * 32;
    const int tx = threadIdx.x & 31, ty = threadIdx.x >> 5;
    const float* ip = in + (long long)b * S * D;
    #pragma unroll
    for (int i = 0; i < 32; i += 8)
        tile[ty + i][tx] = ip[(long long)(s0 + ty + i) * D + d0 + tx];
    __syncthreads();
    ushort* op = out + (long long)b * S * D;
    #pragma unroll
    for (int i = 0; i < 32; i += 8)
        op[(long long)(d0 + ty + i) * S + s0 + tx] = f2bf(tile[tx][ty + i]);
}

// ---------------------------------------------------------------------------
// Softmax write with inlined merge (reads chunk stats pm/ps directly).
// ---------------------------------------------------------------------------
__global__ __launch_bounds__(256) void softmax_write2_kernel(
    float* __restrict__ scores, const float* __restrict__ pm,
    const float* __restrict__ ps, int L, int S, int chlen,
    ushort* __restrict__ wbf)
{
    int s = blockIdx.x * 256 + threadIdx.x;
    int c = blockIdx.y;
    int b = blockIdx.z;

    float m = -INFINITY;
    #pragma unroll
    for (int k = 0; k < SM_CH; ++k)
        m = fmaxf(m, pm[(b * SM_CH + k) * S + s]);
    float sum = 0.f;
    #pragma unroll
    for (int k = 0; k < SM_CH; ++k)
        sum += ps[(b * SM_CH + k) * S + s] * __expf(pm[(b * SM_CH + k) * S + s] - m);
    float inv = 1.f / sum;

    float* p = scores + (long long)b * L * S + s;
    ushort* q = wbf + (long long)b * L * S + s;
    int l0 = c * chlen;
    int l1 = min(L, l0 + chlen);
    for (int l = l0; l < l1; ++l) {
        float x = p[(long long)l * S];
        float v = __expf(x - m) * inv;
        p[(long long)l * S] = v;
        q[(long long)l * S] = f2bf(v);
    }
}

extern "C" void kernel_launch(void* const* d_in, const int* in_sizes, int n_in,
                              void* d_out, int out_size, void* d_ws, size_t ws_size,
                              hipStream_t stream)
{
    const int Bn = 8, S = 512, D = 768, E = 768, L = 4000;
    const float* lhs   = (const float*)d_in[0];   // [B,S,D]
    const float* label = (const float*)d_in[1];   // [L,E]
    const float* W     = (const float*)d_in[2];   // [E,D]
    const float* bias  = (const float*)d_in[3];   // [E]

    float* weights = (float*)d_out;                          // [B,L,S]
    float* attn    = (float*)d_out + (long long)Bn * L * S;  // [B,L,D]

    const long long nLE  = (long long)L * E;        // 3,072,000
    const long long nBSE = (long long)Bn * S * E;   // 3,145,728
    const long long nBDS = (long long)Bn * D * S;   // 3,145,728
    const long long nBLS = (long long)Bn * L * S;   // 16,384,000
    const long long nED  = (long long)E * D;        // 589,824

    ushort* labelH = (ushort*)d_ws;
    ushort* labelL = labelH + nLE;
    ushort* projH  = labelL + nLE;
    ushort* projL  = projH + nBSE;
    ushort* lhsT   = projL + nBSE;
    ushort* wbf    = lhsT + nBDS;
    float*  pm     = (float*)(wbf + nBLS);
    float*  ps     = pm + Bn * SM_CH * S;
    ushort* WH     = (ushort*)(ps + Bn * SM_CH * S);
    ushort* WL     = WH + nED;

    hipFuncSetAttribute((const void*)mfma_sc2,
                        hipFuncAttributeMaxDynamicSharedMemorySize, 131072);
    hipFuncSetAttribute((const void*)mfma_attn8,
                        hipFuncAttributeMaxDynamicSharedMemorySize, 98304);

    // 0) lhsT (bf16 transpose) + label & W hi/lo planes
    transpose_bf16_kernel<<<dim3(S / 32, D / 32, Bn), 256, 0, stream>>>(
        lhs, lhsT, S, D);
    split_planes_kernel<<<(int)(nLE / 4 + 255) / 256, 256, 0, stream>>>(
        label, labelH, labelL, nLE / 4);
    split_planes_kernel<<<(int)(nED / 4 + 255) / 256, 256, 0, stream>>>(
        W, WH, WL, nED / 4);

    // 1) projH/L = split(tanh(lhs @ W^T + bias)), B-side via gload planes
    mfma_proj2<<<dim3((Bn * S) / 128, E / 128, 1), 256, 65536, stream>>>(
        lhs, WH, WL, projH, projL, bias, Bn * S, E, D);

    // 2) scores + fused per-chunk (max,sum): M=L, N=S, K=768, BK=32
    mfma_sc2<<<dim3((L + 255) / 256, S / 256, Bn), 512, 131072, stream>>>(
        labelH, labelL, projH, projL, weights, pm, ps,
        L, S, (long long)S * E, (long long)L * S);

    // 3) softmax write with inlined merge (in place, + bf16 copy)
    softmax_write2_kernel<<<dim3(S / 256, WCH, Bn), 256, 0, stream>>>(
        weights, pm, ps, L, S, (L + WCH - 1) / WCH, wbf);

    // 4) attn = wbf @ lhsT^T: M=L, N=D, K=512
    mfma_attn8<<<dim3((L + 127) / 128, D / 256, Bn), 512, 98304, stream>>>(
        wbf, lhsT, attn, L, D,
        (long long)L * S, (long long)D * S, (long long)L * D);
}

// Round 15
// 234.561 us; speedup vs baseline: 1.0763x; 1.0178x over previous
//
#include <hip/hip_runtime.h>
#include <hip/hip_bf16.h>
#include <cmath>

typedef __attribute__((ext_vector_type(8))) short short8;
typedef __attribute__((ext_vector_type(4))) float f32x4;

#define SM_CH 16   // scores stats chunks: 4000 rows / 256-row blocks -> 16
#define WCH   32   // softmax write-pass chunking

__device__ inline ushort f2bf(float x) {
    union { float f; unsigned u; } v; v.f = x;
    unsigned r = v.u + 0x7FFF + ((v.u >> 16) & 1);   // RNE
    return (ushort)(r >> 16);
}

__device__ inline void split2(float x, ushort& hi, ushort& lo) {
    union { float f; unsigned u; } v; v.f = x;
    hi = (ushort)(v.u >> 16);
    union { float f; unsigned u; } h; h.u = v.u & 0xFFFF0000u;
    union { float f; unsigned u; } d; d.f = x - h.f;
    lo = (ushort)(d.u >> 16);
}

// byte offset within one [rows x 128B] LDS plane, XOR-swizzled (T2).
__device__ inline int swz(int row, int byte_in_row) {
    return row * 128 + (byte_in_row ^ ((row & 7) << 4));
}

// async global->LDS, 16B/lane; lds base wave-uniform, HW adds lane*16.
__device__ inline void gload16(const void* g, void* lds) {
    __builtin_amdgcn_global_load_lds(
        (const __attribute__((address_space(1))) unsigned int*)g,
        (__attribute__((address_space(3))) unsigned int*)lds, 16, 0, 0);
}

// T1: bijective XCD-aware block remap (requires nwg % 8 == 0).
__device__ inline void xcd_remap(int& bx, int& by, int& bz) {
    unsigned nx = gridDim.x, ny = gridDim.y;
    unsigned nwg = nx * ny * gridDim.z;
    unsigned id = blockIdx.x + nx * (blockIdx.y + ny * blockIdx.z);
    unsigned q = nwg >> 3;
    unsigned s = (id & 7) * q + (id >> 3);
    bx = s % nx; unsigned r = s / nx;
    by = r % ny; bz = r / ny;
}

// ---------------------------------------------------------------------------
// scores GEMM v2 (R9-proven): weights[b] = labelHL @ projHL[b]^T, 3-term split.
// BK=32, paired-plane LDS rows: [hi 32k | lo 32k] = 128B. All 4 planes
// staged ONCE per K-tile (64KB, dbuf in 128KB LDS); 24 ds_read feed 96 MFMA.
// Fused per-column (max,sum) partials over the block's 256 rows.
// ---------------------------------------------------------------------------
__global__ __launch_bounds__(512, 2) void mfma_sc2(
    const ushort* __restrict__ AH, const ushort* __restrict__ AL,
    const ushort* __restrict__ BH, const ushort* __restrict__ BL,
    float* __restrict__ Cb, float* __restrict__ pmo, float* __restrict__ pso,
    int M, int N, long long sB, long long sC)
{
    extern __shared__ char smem[];
    // layout: [A0 32K | A1 32K | B0 32K | B1 32K]
    const int K = 768;

    int bx, by, bz; xcd_remap(bx, by, bz);
    const int bm = bx * 256;
    const int bn = by * 256;
    const long long z = bz;

    const ushort* BHb = BH + z * sB;
    const ushort* BLb = BL + z * sB;

    const int t    = threadIdx.x;
    const int lane = t & 63;
    const int w    = t >> 6;
    const int wr   = w >> 2;        // 0..1
    const int wc   = w & 3;         // 0..3
    const int lrow = lane & 15;
    const int kg16 = (lane >> 4) * 16;

    // staging: 4 A-chunks + 4 B-chunks per thread. Physical slot p=lane&7 of
    // row holds logical slot q = p ^ (row&7); q<4 -> hi plane, else lo plane.
    const ushort* srcA[4]; const ushort* srcB[4]; int ldsO[4];
    #pragma unroll
    for (int i = 0; i < 4; ++i) {
        const int row  = w * 32 + i * 8 + (lane >> 3);
        const int q    = (lane & 7) ^ (row & 7);
        const int colo = (q & 3) * 8;
        srcA[i] = ((q < 4) ? AH : AL) + (long long)min(bm + row, M - 1) * K + colo;
        srcB[i] = ((q < 4) ? BHb : BLb) + (long long)(bn + row) * K + colo;
        ldsO[i] = w * 4096 + i * 1024;  // wave-uniform
    }

#define STAGE(k0_, cur_)                                                      \
    {                                                                         \
        _Pragma("unroll")                                                     \
        for (int i = 0; i < 4; ++i) {                                         \
            gload16(srcA[i] + (k0_), smem + (cur_) * 32768 + ldsO[i]);        \
            gload16(srcB[i] + (k0_), smem + 65536 + (cur_) * 32768 + ldsO[i]);\
        }                                                                     \
    }

    // prologue: tiles 0 and 1
    STAGE(0, 0);
    STAGE(32, 1);
    asm volatile("s_waitcnt vmcnt(8)" ::: "memory");
    __builtin_amdgcn_s_barrier();

    f32x4 acc[8][4] = {};

    for (int tt = 0; tt < 24; ++tt) {
        const int cur = tt & 1;
        const char* Ab = smem + cur * 32768;
        const char* Bb = smem + 65536 + cur * 32768;

        __builtin_amdgcn_s_setprio(1);
        short8 bh[4], bl[4];
        #pragma unroll
        for (int n = 0; n < 4; ++n) {
            bh[n] = *(const short8*)(Bb + swz(wc * 64 + n * 16 + lrow, kg16));
            bl[n] = *(const short8*)(Bb + swz(wc * 64 + n * 16 + lrow, 64 + kg16));
        }
        #pragma unroll
        for (int g = 0; g < 2; ++g) {
            short8 ah[4], al[4];
            #pragma unroll
            for (int m4 = 0; m4 < 4; ++m4) {
                const int r = wr * 128 + (g * 4 + m4) * 16 + lrow;
                ah[m4] = *(const short8*)(Ab + swz(r, kg16));
                al[m4] = *(const short8*)(Ab + swz(r, 64 + kg16));
            }
            #pragma unroll
            for (int m4 = 0; m4 < 4; ++m4)
                #pragma unroll
                for (int n = 0; n < 4; ++n) {
                    acc[g*4+m4][n] = __builtin_amdgcn_mfma_f32_16x16x32_bf16(
                        al[m4], bh[n], acc[g*4+m4][n], 0, 0, 0);
                    acc[g*4+m4][n] = __builtin_amdgcn_mfma_f32_16x16x32_bf16(
                        ah[m4], bl[n], acc[g*4+m4][n], 0, 0, 0);
                    acc[g*4+m4][n] = __builtin_amdgcn_mfma_f32_16x16x32_bf16(
                        ah[m4], bh[n], acc[g*4+m4][n], 0, 0, 0);
                }
        }
        __builtin_amdgcn_s_setprio(0);

        asm volatile("s_waitcnt lgkmcnt(0)" ::: "memory");
        __builtin_amdgcn_s_barrier();

        if (tt + 2 < 24) {
            STAGE((tt + 2) * 32, cur);
            asm volatile("s_waitcnt vmcnt(8)" ::: "memory");
        } else {
            asm volatile("s_waitcnt vmcnt(0)" ::: "memory");
        }
        __builtin_amdgcn_s_barrier();
    }
#undef STAGE

    // ---- C write ----
    float* C = Cb + z * sC;
    const int r0 = bm + wr * 128 + (lane >> 4) * 4;
    const int c0 = bn + wc * 64 + (lane & 15);
    #pragma unroll
    for (int n = 0; n < 4; ++n) {
        const int col = c0 + n * 16;
        #pragma unroll
        for (int mi = 0; mi < 8; ++mi) {
            #pragma unroll
            for (int r = 0; r < 4; ++r) {
                const int row = r0 + mi * 16 + r;
                if (row < M) C[(long long)row * N + col] = acc[mi][n][r];
            }
        }
    }

    // ---- fused per-column (max, sum) over the block's 256 rows ----
    __syncthreads();
    float* red = (float*)smem;                       // [256][8]
    const int slot = wr * 4 + (lane >> 4);
    const int colb = wc * 64 + (lane & 15);

    float lm[4];
    #pragma unroll
    for (int n = 0; n < 4; ++n) {
        float v = -INFINITY;
        #pragma unroll
        for (int mi = 0; mi < 8; ++mi)
            #pragma unroll
            for (int r = 0; r < 4; ++r)
                if (r0 + mi * 16 + r < M) v = fmaxf(v, acc[mi][n][r]);
        lm[n] = v;
    }
    #pragma unroll
    for (int n = 0; n < 4; ++n)
        red[(colb + n * 16) * 8 + slot] = lm[n];
    __syncthreads();
    float cm[4];
    #pragma unroll
    for (int n = 0; n < 4; ++n) {
        float v = -INFINITY;
        #pragma unroll
        for (int s8 = 0; s8 < 8; ++s8)
            v = fmaxf(v, red[(colb + n * 16) * 8 + s8]);
        cm[n] = v;
    }
    __syncthreads();
    float ls[4];
    #pragma unroll
    for (int n = 0; n < 4; ++n) {
        float sum = 0.f;
        #pragma unroll
        for (int mi = 0; mi < 8; ++mi)
            #pragma unroll
            for (int r = 0; r < 4; ++r)
                if (r0 + mi * 16 + r < M) sum += __expf(acc[mi][n][r] - cm[n]);
        ls[n] = sum;
    }
    #pragma unroll
    for (int n = 0; n < 4; ++n)
        red[(colb + n * 16) * 8 + slot] = ls[n];
    __syncthreads();
    if (slot == 0) {
        #pragma unroll
        for (int n = 0; n < 4; ++n) {
            float sum = 0.f;
            #pragma unroll
            for (int s8 = 0; s8 < 8; ++s8)
                sum += red[(colb + n * 16) * 8 + s8];
            const int col = bn + colb + n * 16;
            pmo[(z * SM_CH + bx) * N + col] = cm[n];
            pso[(z * SM_CH + bx) * N + col] = sum;
        }
    }
}

// ---------------------------------------------------------------------------
// attn GEMM (R8/R9/R11-proven): 8-wave, BM=128 x BN=256, BK=64, dbuf,
// counted vmcnt.
// ---------------------------------------------------------------------------
template<int ROWS, int KS>
__device__ inline void stage_plane(const ushort* __restrict__ src,
                                   char* plane, int t, int rbase, int rmax)
{
    #pragma unroll
    for (int s = 0; s < ROWS / 64; ++s) {
        const int row = s * 64 + (t >> 3);
        const int col = (((t & 7) * 16) ^ ((row & 7) << 4)) >> 1;  // elems
        const int gr  = min(rbase + row, rmax);
        gload16(src + (long long)gr * KS + col,
                plane + s * 8192 + (t >> 6) * 1024);
    }
}

__global__ __launch_bounds__(512, 2) void mfma_attn8(
    const ushort* __restrict__ A, const ushort* __restrict__ B,
    float* __restrict__ Cb, int M, int N,
    long long sA, long long sB, long long sC)
{
    extern __shared__ char smem[];
    constexpr int ABYTES = 128 * 128;   // one A buffer (BM=128)
    constexpr int NT = 8, KS = 512;

    int bx, by, bz; xcd_remap(bx, by, bz);
    const int bm = bx * 128;
    const int bn = by * 256;
    const long long z = bz;

    const ushort* Ab_g = A + z * sA;
    const ushort* Bb_g = B + z * sB;

    const int t    = threadIdx.x;
    const int lane = t & 63;
    const int w    = t >> 6;
    const int wr   = w >> 2;
    const int wc   = w & 3;
    const int lrow = lane & 15;
    const int kg16 = (lane >> 4) * 16;

    stage_plane<128, KS>(Ab_g, smem, t, bm, M - 1);
    stage_plane<256, KS>(Bb_g, smem + 2 * ABYTES, t, bn, N - 1);
    stage_plane<128, KS>(Ab_g + 64, smem + ABYTES, t, bm, M - 1);
    stage_plane<256, KS>(Bb_g + 64, smem + 2 * ABYTES + 32768, t, bn, N - 1);
    asm volatile("s_waitcnt vmcnt(6)" ::: "memory");
    __builtin_amdgcn_s_barrier();

    f32x4 acc[4][4] = {};

    for (int tt = 0; tt < NT; ++tt) {
        const int cur = tt & 1;
        char* Ab = smem + cur * ABYTES;
        char* Bb = smem + 2 * ABYTES + cur * 32768;

        __builtin_amdgcn_s_setprio(1);
        short8 bf[4][2];
        #pragma unroll
        for (int n = 0; n < 4; ++n)
            #pragma unroll
            for (int ks = 0; ks < 2; ++ks)
                bf[n][ks] = *(const short8*)(Bb + swz(wc * 64 + n * 16 + lrow,
                                                      ks * 64 + kg16));
        #pragma unroll
        for (int q = 0; q < 2; ++q) {
            short8 af[2][2];
            #pragma unroll
            for (int mi = 0; mi < 2; ++mi)
                #pragma unroll
                for (int ks = 0; ks < 2; ++ks)
                    af[mi][ks] = *(const short8*)(Ab +
                        swz(wr * 64 + (q * 2 + mi) * 16 + lrow, ks * 64 + kg16));
            #pragma unroll
            for (int ks = 0; ks < 2; ++ks)
                #pragma unroll
                for (int mi = 0; mi < 2; ++mi)
                    #pragma unroll
                    for (int n = 0; n < 4; ++n)
                        acc[q * 2 + mi][n] = __builtin_amdgcn_mfma_f32_16x16x32_bf16(
                            af[mi][ks], bf[n][ks], acc[q * 2 + mi][n], 0, 0, 0);
        }
        __builtin_amdgcn_s_setprio(0);

        asm volatile("s_waitcnt lgkmcnt(0)" ::: "memory");
        __builtin_amdgcn_s_barrier();

        if (tt + 2 < NT) {
            stage_plane<128, KS>(Ab_g + (tt + 2) * 64, smem + cur * ABYTES,
                                 t, bm, M - 1);
            stage_plane<256, KS>(Bb_g + (tt + 2) * 64,
                                 smem + 2 * ABYTES + cur * 32768, t, bn, N - 1);
            asm volatile("s_waitcnt vmcnt(6)" ::: "memory");
        } else {
            asm volatile("s_waitcnt vmcnt(0)" ::: "memory");
        }
        __builtin_amdgcn_s_barrier();
    }

    float* C = Cb + z * sC;
    const int r0 = bm + wr * 64 + (lane >> 4) * 4;
    const int c0 = bn + wc * 64 + (lane & 15);
    #pragma unroll
    for (int n = 0; n < 4; ++n) {
        const int col = c0 + n * 16;
        #pragma unroll
        for (int mi = 0; mi < 4; ++mi) {
            #pragma unroll
            for (int r = 0; r < 4; ++r) {
                const int row = r0 + mi * 16 + r;
                if (row < M) C[(long long)row * N + col] = acc[mi][n][r];
            }
        }
    }
}

// ---------------------------------------------------------------------------
// Fused prep: transpose lhs -> lhsT bf16 (blocks [0,3072)), split label
// (blocks [3072,6072)), split W (blocks [6072,6648)). Disjoint outputs,
// identical per-element math to the R14 kernels.
// ---------------------------------------------------------------------------
__global__ __launch_bounds__(256) void prep_kernel(
    const float* __restrict__ lhs, ushort* __restrict__ lhsT,
    const float* __restrict__ label, ushort* __restrict__ labelH,
    ushort* __restrict__ labelL,
    const float* __restrict__ W, ushort* __restrict__ WH,
    ushort* __restrict__ WL,
    int S, int D, long long nLE4, long long nED4)
{
    const int bid = blockIdx.x;
    if (bid < 3072) {
        // transpose: grid was (S/32=16, D/32=24, Bn=8)
        __shared__ float tile[32][33];
        const int sx = bid & 15;
        const int dy = (bid >> 4) % 24;
        const int b  = bid / (16 * 24);
        const int s0 = sx * 32, d0 = dy * 32;
        const int tx = threadIdx.x & 31, ty = threadIdx.x >> 5;
        const float* ip = lhs + (long long)b * S * D;
        #pragma unroll
        for (int i = 0; i < 32; i += 8)
            tile[ty + i][tx] = ip[(long long)(s0 + ty + i) * D + d0 + tx];
        __syncthreads();
        ushort* op = lhsT + (long long)b * S * D;
        #pragma unroll
        for (int i = 0; i < 32; i += 8)
            op[(long long)(d0 + ty + i) * S + s0 + tx] = f2bf(tile[tx][ty + i]);
    } else if (bid < 6072) {
        long long i = (long long)(bid - 3072) * 256 + threadIdx.x;
        if (i < nLE4) {
            float4 v = *(const float4*)(label + i * 4);
            ushort h[4], l[4];
            split2(v.x, h[0], l[0]); split2(v.y, h[1], l[1]);
            split2(v.z, h[2], l[2]); split2(v.w, h[3], l[3]);
            *(ushort4*)(labelH + i * 4) = *(ushort4*)h;
            *(ushort4*)(labelL + i * 4) = *(ushort4*)l;
        }
    } else {
        long long i = (long long)(bid - 6072) * 256 + threadIdx.x;
        if (i < nED4) {
            float4 v = *(const float4*)(W + i * 4);
            ushort h[4], l[4];
            split2(v.x, h[0], l[0]); split2(v.y, h[1], l[1]);
            split2(v.z, h[2], l[2]); split2(v.w, h[3], l[3]);
            *(ushort4*)(WH + i * 4) = *(ushort4*)h;
            *(ushort4*)(WL + i * 4) = *(ushort4*)l;
        }
    }
}

// ---------------------------------------------------------------------------
// proj GEMM v2 (R14-proven): A=lhs f32 reg-split, B = WH/WL bf16 planes via
// global_load_lds. tanh+split epilogue. LDS 64KB: Ah@0 Al@16K Bh@32K Bl@48K.
// ---------------------------------------------------------------------------
__global__ __launch_bounds__(256) void mfma_proj2(
    const float* __restrict__ Ab, const ushort* __restrict__ WH,
    const ushort* __restrict__ WL, ushort* __restrict__ CH,
    ushort* __restrict__ CL, const float* __restrict__ bias,
    int M, int N, int K)
{
    extern __shared__ char smem[];
    char* Ah = smem;
    char* Al = smem + 16384;
    char* Bh = smem + 32768;
    char* Bl = smem + 49152;

    int bx, by, bz; xcd_remap(bx, by, bz);
    const int bm = bx * 128;
    const int bn = by * 128;

    const int t    = threadIdx.x;
    const int lane = t & 63;
    const int w    = t >> 6;

    // A reg-staging (f32 -> hi/lo split in registers)
    const int srow = t >> 1;
    const int skh  = (t & 1) * 32;
    const float* ap = Ab + (long long)min(bm + srow, M - 1) * K + skh;

    // B gload: lane's fixed (row, col), inverse-swizzled source
    const int lr  = lane >> 3;
    const int lc8 = 8 * ((lane & 7) ^ lr);
    const ushort* bh_src[4]; const ushort* bl_src[4];
    int ldsB[4];
    #pragma unroll
    for (int i = 0; i < 4; ++i) {
        const int row = w * 32 + i * 8 + lr;
        bh_src[i] = WH + (long long)(bn + row) * K + lc8;
        bl_src[i] = WL + (long long)(bn + row) * K + lc8;
        ldsB[i] = w * 4096 + i * 1024;
    }

    const int wm   = (w >> 1) * 64;
    const int wn   = (w & 1) * 64;
    const int lrow = lane & 15;
    const int kg16 = (lane >> 4) * 16;

    f32x4 acc[4][4] = {};

    for (int k0 = 0; k0 < K; k0 += 64) {
        #pragma unroll
        for (int i = 0; i < 4; ++i) {
            gload16(bh_src[i] + k0, Bh + ldsB[i]);
            gload16(bl_src[i] + k0, Bl + ldsB[i]);
        }
        #pragma unroll
        for (int j = 0; j < 4; ++j) {
            float xs[8];
            *(float4*)&xs[0] = *(const float4*)(ap + k0 + j * 8);
            *(float4*)&xs[4] = *(const float4*)(ap + k0 + j * 8 + 4);
            ushort oh[8], ol[8];
            #pragma unroll
            for (int i = 0; i < 8; ++i) split2(xs[i], oh[i], ol[i]);
            const int off = swz(srow, skh * 2 + j * 16);
            *(uint4*)(Ah + off) = *(uint4*)oh;
            *(uint4*)(Al + off) = *(uint4*)ol;
        }
        __syncthreads();

        #pragma unroll
        for (int kk = 0; kk < 2; ++kk) {
            short8 ah[4], al[4];
            #pragma unroll
            for (int mi = 0; mi < 4; ++mi) {
                const int off = swz(wm + mi * 16 + lrow, kk * 64 + kg16);
                ah[mi] = *(const short8*)(Ah + off);
                al[mi] = *(const short8*)(Al + off);
            }
            #pragma unroll
            for (int ni = 0; ni < 4; ++ni) {
                const int off = swz(wn + ni * 16 + lrow, kk * 64 + kg16);
                short8 bh = *(const short8*)(Bh + off);
                short8 bl = *(const short8*)(Bl + off);
                #pragma unroll
                for (int mi = 0; mi < 4; ++mi) {
                    acc[mi][ni] = __builtin_amdgcn_mfma_f32_16x16x32_bf16(al[mi], bh, acc[mi][ni], 0, 0, 0);
                    acc[mi][ni] = __builtin_amdgcn_mfma_f32_16x16x32_bf16(ah[mi], bl, acc[mi][ni], 0, 0, 0);
                    acc[mi][ni] = __builtin_amdgcn_mfma_f32_16x16x32_bf16(ah[mi], bh, acc[mi][ni], 0, 0, 0);
                }
            }
        }
        __syncthreads();
    }

    const int r0 = bm + wm + (lane >> 4) * 4;
    const int c0 = bn + wn + (lane & 15);
    #pragma unroll
    for (int ni = 0; ni < 4; ++ni) {
        const int col = c0 + ni * 16;
        const float bv = bias[col];
        #pragma unroll
        for (int mi = 0; mi < 4; ++mi) {
            #pragma unroll
            for (int r = 0; r < 4; ++r) {
                const int row = r0 + mi * 16 + r;
                if (row < M) {
                    float x = tanhf(acc[mi][ni][r] + bv);
                    ushort h, l;
                    split2(x, h, l);
                    CH[(long long)row * N + col] = h;
                    CL[(long long)row * N + col] = l;
                }
            }
        }
    }
}

// ---------------------------------------------------------------------------
// Softmax write with inlined merge (reads chunk stats pm/ps directly).
// ---------------------------------------------------------------------------
__global__ __launch_bounds__(256) void softmax_write2_kernel(
    float* __restrict__ scores, const float* __restrict__ pm,
    const float* __restrict__ ps, int L, int S, int chlen,
    ushort* __restrict__ wbf)
{
    int s = blockIdx.x * 256 + threadIdx.x;
    int c = blockIdx.y;
    int b = blockIdx.z;

    float m = -INFINITY;
    #pragma unroll
    for (int k = 0; k < SM_CH; ++k)
        m = fmaxf(m, pm[(b * SM_CH + k) * S + s]);
    float sum = 0.f;
    #pragma unroll
    for (int k = 0; k < SM_CH; ++k)
        sum += ps[(b * SM_CH + k) * S + s] * __expf(pm[(b * SM_CH + k) * S + s] - m);
    float inv = 1.f / sum;

    float* p = scores + (long long)b * L * S + s;
    ushort* q = wbf + (long long)b * L * S + s;
    int l0 = c * chlen;
    int l1 = min(L, l0 + chlen);
    for (int l = l0; l < l1; ++l) {
        float x = p[(long long)l * S];
        float v = __expf(x - m) * inv;
        p[(long long)l * S] = v;
        q[(long long)l * S] = f2bf(v);
    }
}

extern "C" void kernel_launch(void* const* d_in, const int* in_sizes, int n_in,
                              void* d_out, int out_size, void* d_ws, size_t ws_size,
                              hipStream_t stream)
{
    const int Bn = 8, S = 512, D = 768, E = 768, L = 4000;
    const float* lhs   = (const float*)d_in[0];   // [B,S,D]
    const float* label = (const float*)d_in[1];   // [L,E]
    const float* W     = (const float*)d_in[2];   // [E,D]
    const float* bias  = (const float*)d_in[3];   // [E]

    float* weights = (float*)d_out;                          // [B,L,S]
    float* attn    = (float*)d_out + (long long)Bn * L * S;  // [B,L,D]

    const long long nLE  = (long long)L * E;        // 3,072,000
    const long long nBSE = (long long)Bn * S * E;   // 3,145,728
    const long long nBDS = (long long)Bn * D * S;   // 3,145,728
    const long long nBLS = (long long)Bn * L * S;   // 16,384,000
    const long long nED  = (long long)E * D;        // 589,824

    ushort* labelH = (ushort*)d_ws;
    ushort* labelL = labelH + nLE;
    ushort* projH  = labelL + nLE;
    ushort* projL  = projH + nBSE;
    ushort* lhsT   = projL + nBSE;
    ushort* wbf    = lhsT + nBDS;
    float*  pm     = (float*)(wbf + nBLS);
    float*  ps     = pm + Bn * SM_CH * S;
    ushort* WH     = (ushort*)(ps + Bn * SM_CH * S);
    ushort* WL     = WH + nED;

    hipFuncSetAttribute((const void*)mfma_sc2,
                        hipFuncAttributeMaxDynamicSharedMemorySize, 131072);
    hipFuncSetAttribute((const void*)mfma_attn8,
                        hipFuncAttributeMaxDynamicSharedMemorySize, 98304);

    // 0) fused prep: lhsT transpose + label planes + W planes (one launch)
    // blocks: 3072 transpose | 3000 label (nLE/4=768000 elems4) | 576 W
    prep_kernel<<<6648, 256, 0, stream>>>(
        lhs, lhsT, label, labelH, labelL, W, WH, WL,
        S, D, nLE / 4, nED / 4);

    // 1) projH/L = split(tanh(lhs @ W^T + bias)), B-side via gload planes
    mfma_proj2<<<dim3((Bn * S) / 128, E / 128, 1), 256, 65536, stream>>>(
        lhs, WH, WL, projH, projL, bias, Bn * S, E, D);

    // 2) scores + fused per-chunk (max,sum): M=L, N=S, K=768, BK=32
    mfma_sc2<<<dim3((L + 255) / 256, S / 256, Bn), 512, 131072, stream>>>(
        labelH, labelL, projH, projL, weights, pm, ps,
        L, S, (long long)S * E, (long long)L * S);

    // 3) softmax write with inlined merge (in place, + bf16 copy)
    softmax_write2_kernel<<<dim3(S / 256, WCH, Bn), 256, 0, stream>>>(
        weights, pm, ps, L, S, (L + WCH - 1) / WCH, wbf);

    // 4) attn = wbf @ lhsT^T: M=L, N=D, K=512
    mfma_attn8<<<dim3((L + 127) / 128, D / 256, Bn), 512, 98304, stream>>>(
        wbf, lhsT, attn, L, D,
        (long long)L * S, (long long)D * S, (long long)L * D);
}

// Round 16
// 232.870 us; speedup vs baseline: 1.0841x; 1.0073x over previous
//
#include <hip/hip_runtime.h>
#include <hip/hip_bf16.h>
#include <cmath>

typedef __attribute__((ext_vector_type(8))) short short8;
typedef __attribute__((ext_vector_type(4))) float f32x4;

#define SM_CH 16   // scores stats chunks: 4000 rows / 256-row blocks -> 16
#define WCH   32   // softmax write-pass chunking

__device__ inline ushort f2bf(float x) {
    union { float f; unsigned u; } v; v.f = x;
    unsigned r = v.u + 0x7FFF + ((v.u >> 16) & 1);   // RNE
    return (ushort)(r >> 16);
}

__device__ inline void split2(float x, ushort& hi, ushort& lo) {
    union { float f; unsigned u; } v; v.f = x;
    hi = (ushort)(v.u >> 16);
    union { float f; unsigned u; } h; h.u = v.u & 0xFFFF0000u;
    union { float f; unsigned u; } d; d.f = x - h.f;
    lo = (ushort)(d.u >> 16);
}

// byte offset within one [rows x 128B] LDS plane, XOR-swizzled (T2).
__device__ inline int swz(int row, int byte_in_row) {
    return row * 128 + (byte_in_row ^ ((row & 7) << 4));
}

// async global->LDS, 16B/lane; lds base wave-uniform, HW adds lane*16.
__device__ inline void gload16(const void* g, void* lds) {
    __builtin_amdgcn_global_load_lds(
        (const __attribute__((address_space(1))) unsigned int*)g,
        (__attribute__((address_space(3))) unsigned int*)lds, 16, 0, 0);
}

// T1: bijective XCD-aware block remap (requires nwg % 8 == 0).
__device__ inline void xcd_remap(int& bx, int& by, int& bz) {
    unsigned nx = gridDim.x, ny = gridDim.y;
    unsigned nwg = nx * ny * gridDim.z;
    unsigned id = blockIdx.x + nx * (blockIdx.y + ny * blockIdx.z);
    unsigned q = nwg >> 3;
    unsigned s = (id & 7) * q + (id >> 3);
    bx = s % nx; unsigned r = s / nx;
    by = r % ny; bz = r / ny;
}

// ---------------------------------------------------------------------------
// scores GEMM v2 (R9-proven): weights[b] = labelHL @ projHL[b]^T, 3-term split.
// ---------------------------------------------------------------------------
__global__ __launch_bounds__(512, 2) void mfma_sc2(
    const ushort* __restrict__ AH, const ushort* __restrict__ AL,
    const ushort* __restrict__ BH, const ushort* __restrict__ BL,
    float* __restrict__ Cb, float* __restrict__ pmo, float* __restrict__ pso,
    int M, int N, long long sB, long long sC)
{
    extern __shared__ char smem[];
    const int K = 768;

    int bx, by, bz; xcd_remap(bx, by, bz);
    const int bm = bx * 256;
    const int bn = by * 256;
    const long long z = bz;

    const ushort* BHb = BH + z * sB;
    const ushort* BLb = BL + z * sB;

    const int t    = threadIdx.x;
    const int lane = t & 63;
    const int w    = t >> 6;
    const int wr   = w >> 2;        // 0..1
    const int wc   = w & 3;         // 0..3
    const int lrow = lane & 15;
    const int kg16 = (lane >> 4) * 16;

    const ushort* srcA[4]; const ushort* srcB[4]; int ldsO[4];
    #pragma unroll
    for (int i = 0; i < 4; ++i) {
        const int row  = w * 32 + i * 8 + (lane >> 3);
        const int q    = (lane & 7) ^ (row & 7);
        const int colo = (q & 3) * 8;
        srcA[i] = ((q < 4) ? AH : AL) + (long long)min(bm + row, M - 1) * K + colo;
        srcB[i] = ((q < 4) ? BHb : BLb) + (long long)(bn + row) * K + colo;
        ldsO[i] = w * 4096 + i * 1024;  // wave-uniform
    }

#define STAGE(k0_, cur_)                                                      \
    {                                                                         \
        _Pragma("unroll")                                                     \
        for (int i = 0; i < 4; ++i) {                                         \
            gload16(srcA[i] + (k0_), smem + (cur_) * 32768 + ldsO[i]);        \
            gload16(srcB[i] + (k0_), smem + 65536 + (cur_) * 32768 + ldsO[i]);\
        }                                                                     \
    }

    STAGE(0, 0);
    STAGE(32, 1);
    asm volatile("s_waitcnt vmcnt(8)" ::: "memory");
    __builtin_amdgcn_s_barrier();

    f32x4 acc[8][4] = {};

    for (int tt = 0; tt < 24; ++tt) {
        const int cur = tt & 1;
        const char* Ab = smem + cur * 32768;
        const char* Bb = smem + 65536 + cur * 32768;

        __builtin_amdgcn_s_setprio(1);
        short8 bh[4], bl[4];
        #pragma unroll
        for (int n = 0; n < 4; ++n) {
            bh[n] = *(const short8*)(Bb + swz(wc * 64 + n * 16 + lrow, kg16));
            bl[n] = *(const short8*)(Bb + swz(wc * 64 + n * 16 + lrow, 64 + kg16));
        }
        #pragma unroll
        for (int g = 0; g < 2; ++g) {
            short8 ah[4], al[4];
            #pragma unroll
            for (int m4 = 0; m4 < 4; ++m4) {
                const int r = wr * 128 + (g * 4 + m4) * 16 + lrow;
                ah[m4] = *(const short8*)(Ab + swz(r, kg16));
                al[m4] = *(const short8*)(Ab + swz(r, 64 + kg16));
            }
            #pragma unroll
            for (int m4 = 0; m4 < 4; ++m4)
                #pragma unroll
                for (int n = 0; n < 4; ++n) {
                    acc[g*4+m4][n] = __builtin_amdgcn_mfma_f32_16x16x32_bf16(
                        al[m4], bh[n], acc[g*4+m4][n], 0, 0, 0);
                    acc[g*4+m4][n] = __builtin_amdgcn_mfma_f32_16x16x32_bf16(
                        ah[m4], bl[n], acc[g*4+m4][n], 0, 0, 0);
                    acc[g*4+m4][n] = __builtin_amdgcn_mfma_f32_16x16x32_bf16(
                        ah[m4], bh[n], acc[g*4+m4][n], 0, 0, 0);
                }
        }
        __builtin_amdgcn_s_setprio(0);

        asm volatile("s_waitcnt lgkmcnt(0)" ::: "memory");
        __builtin_amdgcn_s_barrier();

        if (tt + 2 < 24) {
            STAGE((tt + 2) * 32, cur);
            asm volatile("s_waitcnt vmcnt(8)" ::: "memory");
        } else {
            asm volatile("s_waitcnt vmcnt(0)" ::: "memory");
        }
        __builtin_amdgcn_s_barrier();
    }
#undef STAGE

    float* C = Cb + z * sC;
    const int r0 = bm + wr * 128 + (lane >> 4) * 4;
    const int c0 = bn + wc * 64 + (lane & 15);
    #pragma unroll
    for (int n = 0; n < 4; ++n) {
        const int col = c0 + n * 16;
        #pragma unroll
        for (int mi = 0; mi < 8; ++mi) {
            #pragma unroll
            for (int r = 0; r < 4; ++r) {
                const int row = r0 + mi * 16 + r;
                if (row < M) C[(long long)row * N + col] = acc[mi][n][r];
            }
        }
    }

    __syncthreads();
    float* red = (float*)smem;                       // [256][8]
    const int slot = wr * 4 + (lane >> 4);
    const int colb = wc * 64 + (lane & 15);

    float lm[4];
    #pragma unroll
    for (int n = 0; n < 4; ++n) {
        float v = -INFINITY;
        #pragma unroll
        for (int mi = 0; mi < 8; ++mi)
            #pragma unroll
            for (int r = 0; r < 4; ++r)
                if (r0 + mi * 16 + r < M) v = fmaxf(v, acc[mi][n][r]);
        lm[n] = v;
    }
    #pragma unroll
    for (int n = 0; n < 4; ++n)
        red[(colb + n * 16) * 8 + slot] = lm[n];
    __syncthreads();
    float cm[4];
    #pragma unroll
    for (int n = 0; n < 4; ++n) {
        float v = -INFINITY;
        #pragma unroll
        for (int s8 = 0; s8 < 8; ++s8)
            v = fmaxf(v, red[(colb + n * 16) * 8 + s8]);
        cm[n] = v;
    }
    __syncthreads();
    float ls[4];
    #pragma unroll
    for (int n = 0; n < 4; ++n) {
        float sum = 0.f;
        #pragma unroll
        for (int mi = 0; mi < 8; ++mi)
            #pragma unroll
            for (int r = 0; r < 4; ++r)
                if (r0 + mi * 16 + r < M) sum += __expf(acc[mi][n][r] - cm[n]);
        ls[n] = sum;
    }
    #pragma unroll
    for (int n = 0; n < 4; ++n)
        red[(colb + n * 16) * 8 + slot] = ls[n];
    __syncthreads();
    if (slot == 0) {
        #pragma unroll
        for (int n = 0; n < 4; ++n) {
            float sum = 0.f;
            #pragma unroll
            for (int s8 = 0; s8 < 8; ++s8)
                sum += red[(colb + n * 16) * 8 + s8];
            const int col = bn + colb + n * 16;
            pmo[(z * SM_CH + bx) * N + col] = cm[n];
            pso[(z * SM_CH + bx) * N + col] = sum;
        }
    }
}

// ---------------------------------------------------------------------------
// attn GEMM (R8/R9/R11-proven): 8-wave, BM=128 x BN=256, BK=64, dbuf,
// counted vmcnt.
// ---------------------------------------------------------------------------
template<int ROWS, int KS>
__device__ inline void stage_plane(const ushort* __restrict__ src,
                                   char* plane, int t, int rbase, int rmax)
{
    #pragma unroll
    for (int s = 0; s < ROWS / 64; ++s) {
        const int row = s * 64 + (t >> 3);
        const int col = (((t & 7) * 16) ^ ((row & 7) << 4)) >> 1;  // elems
        const int gr  = min(rbase + row, rmax);
        gload16(src + (long long)gr * KS + col,
                plane + s * 8192 + (t >> 6) * 1024);
    }
}

__global__ __launch_bounds__(512, 2) void mfma_attn8(
    const ushort* __restrict__ A, const ushort* __restrict__ B,
    float* __restrict__ Cb, int M, int N,
    long long sA, long long sB, long long sC)
{
    extern __shared__ char smem[];
    constexpr int ABYTES = 128 * 128;   // one A buffer (BM=128)
    constexpr int NT = 8, KS = 512;

    int bx, by, bz; xcd_remap(bx, by, bz);
    const int bm = bx * 128;
    const int bn = by * 256;
    const long long z = bz;

    const ushort* Ab_g = A + z * sA;
    const ushort* Bb_g = B + z * sB;

    const int t    = threadIdx.x;
    const int lane = t & 63;
    const int w    = t >> 6;
    const int wr   = w >> 2;
    const int wc   = w & 3;
    const int lrow = lane & 15;
    const int kg16 = (lane >> 4) * 16;

    stage_plane<128, KS>(Ab_g, smem, t, bm, M - 1);
    stage_plane<256, KS>(Bb_g, smem + 2 * ABYTES, t, bn, N - 1);
    stage_plane<128, KS>(Ab_g + 64, smem + ABYTES, t, bm, M - 1);
    stage_plane<256, KS>(Bb_g + 64, smem + 2 * ABYTES + 32768, t, bn, N - 1);
    asm volatile("s_waitcnt vmcnt(6)" ::: "memory");
    __builtin_amdgcn_s_barrier();

    f32x4 acc[4][4] = {};

    for (int tt = 0; tt < NT; ++tt) {
        const int cur = tt & 1;
        char* Ab = smem + cur * ABYTES;
        char* Bb = smem + 2 * ABYTES + cur * 32768;

        __builtin_amdgcn_s_setprio(1);
        short8 bf[4][2];
        #pragma unroll
        for (int n = 0; n < 4; ++n)
            #pragma unroll
            for (int ks = 0; ks < 2; ++ks)
                bf[n][ks] = *(const short8*)(Bb + swz(wc * 64 + n * 16 + lrow,
                                                      ks * 64 + kg16));
        #pragma unroll
        for (int q = 0; q < 2; ++q) {
            short8 af[2][2];
            #pragma unroll
            for (int mi = 0; mi < 2; ++mi)
                #pragma unroll
                for (int ks = 0; ks < 2; ++ks)
                    af[mi][ks] = *(const short8*)(Ab +
                        swz(wr * 64 + (q * 2 + mi) * 16 + lrow, ks * 64 + kg16));
            #pragma unroll
            for (int ks = 0; ks < 2; ++ks)
                #pragma unroll
                for (int mi = 0; mi < 2; ++mi)
                    #pragma unroll
                    for (int n = 0; n < 4; ++n)
                        acc[q * 2 + mi][n] = __builtin_amdgcn_mfma_f32_16x16x32_bf16(
                            af[mi][ks], bf[n][ks], acc[q * 2 + mi][n], 0, 0, 0);
        }
        __builtin_amdgcn_s_setprio(0);

        asm volatile("s_waitcnt lgkmcnt(0)" ::: "memory");
        __builtin_amdgcn_s_barrier();

        if (tt + 2 < NT) {
            stage_plane<128, KS>(Ab_g + (tt + 2) * 64, smem + cur * ABYTES,
                                 t, bm, M - 1);
            stage_plane<256, KS>(Bb_g + (tt + 2) * 64,
                                 smem + 2 * ABYTES + cur * 32768, t, bn, N - 1);
            asm volatile("s_waitcnt vmcnt(6)" ::: "memory");
        } else {
            asm volatile("s_waitcnt vmcnt(0)" ::: "memory");
        }
        __builtin_amdgcn_s_barrier();
    }

    float* C = Cb + z * sC;
    const int r0 = bm + wr * 64 + (lane >> 4) * 4;
    const int c0 = bn + wc * 64 + (lane & 15);
    #pragma unroll
    for (int n = 0; n < 4; ++n) {
        const int col = c0 + n * 16;
        #pragma unroll
        for (int mi = 0; mi < 4; ++mi) {
            #pragma unroll
            for (int r = 0; r < 4; ++r) {
                const int row = r0 + mi * 16 + r;
                if (row < M) C[(long long)row * N + col] = acc[mi][n][r];
            }
        }
    }
}

// ---------------------------------------------------------------------------
// split f32 array -> hi/lo bf16 planes (W only now; must precede proj)
// ---------------------------------------------------------------------------
__global__ __launch_bounds__(256) void split_planes_kernel(
    const float* __restrict__ in, ushort* __restrict__ H,
    ushort* __restrict__ L, long long n4)
{
    long long i = (long long)blockIdx.x * 256 + threadIdx.x;
    if (i >= n4) return;
    float4 v = *(const float4*)(in + i * 4);
    ushort h[4], l[4];
    split2(v.x, h[0], l[0]); split2(v.y, h[1], l[1]);
    split2(v.z, h[2], l[2]); split2(v.w, h[3], l[3]);
    *(ushort4*)(H + i * 4) = *(ushort4*)h;
    *(ushort4*)(L + i * 4) = *(ushort4*)l;
}

// ---------------------------------------------------------------------------
// Fused proj GEMM + prep: blocks [0,192) = proj2 GEMM (R14-proven body);
// [192,3264) = lhs->lhsT bf16 transpose; [3264,6264) = label hi/lo split.
// lhsT/labelH/labelL are consumed only by LATER launches (sc2/attn8), so
// running them concurrently with the GEMM blocks is safe (disjoint outputs).
// The prep blocks soak the ~160 CUs the 192-block GEMM leaves idle.
// ---------------------------------------------------------------------------
__global__ __launch_bounds__(256) void proj_prep_kernel(
    const float* __restrict__ lhs, const ushort* __restrict__ WH,
    const ushort* __restrict__ WL, ushort* __restrict__ CH,
    ushort* __restrict__ CL, const float* __restrict__ bias,
    ushort* __restrict__ lhsT, const float* __restrict__ label,
    ushort* __restrict__ labelH, ushort* __restrict__ labelL,
    int M, int N, int K, int S, int D, long long nLE4)
{
    extern __shared__ char smem[];
    const int bid = blockIdx.x;

    if (bid < 192) {
        // ---- proj GEMM (bijective XCD remap over the 192-block sub-grid) ----
        char* Ah = smem;
        char* Al = smem + 16384;
        char* Bh = smem + 32768;
        char* Bl = smem + 49152;

        const unsigned sswz = (bid & 7) * 24 + (bid >> 3);   // nwg=192, q=24
        const int bx = sswz % 32, by = sswz / 32;
        const int bm = bx * 128;
        const int bn = by * 128;

        const int t    = threadIdx.x;
        const int lane = t & 63;
        const int w    = t >> 6;

        const int srow = t >> 1;
        const int skh  = (t & 1) * 32;
        const float* ap = lhs + (long long)min(bm + srow, M - 1) * K + skh;

        const int lr  = lane >> 3;
        const int lc8 = 8 * ((lane & 7) ^ lr);
        const ushort* bh_src[4]; const ushort* bl_src[4];
        int ldsB[4];
        #pragma unroll
        for (int i = 0; i < 4; ++i) {
            const int row = w * 32 + i * 8 + lr;
            bh_src[i] = WH + (long long)(bn + row) * K + lc8;
            bl_src[i] = WL + (long long)(bn + row) * K + lc8;
            ldsB[i] = w * 4096 + i * 1024;
        }

        const int wm   = (w >> 1) * 64;
        const int wn   = (w & 1) * 64;
        const int lrow = lane & 15;
        const int kg16 = (lane >> 4) * 16;

        f32x4 acc[4][4] = {};

        for (int k0 = 0; k0 < K; k0 += 64) {
            #pragma unroll
            for (int i = 0; i < 4; ++i) {
                gload16(bh_src[i] + k0, Bh + ldsB[i]);
                gload16(bl_src[i] + k0, Bl + ldsB[i]);
            }
            #pragma unroll
            for (int j = 0; j < 4; ++j) {
                float xs[8];
                *(float4*)&xs[0] = *(const float4*)(ap + k0 + j * 8);
                *(float4*)&xs[4] = *(const float4*)(ap + k0 + j * 8 + 4);
                ushort oh[8], ol[8];
                #pragma unroll
                for (int i = 0; i < 8; ++i) split2(xs[i], oh[i], ol[i]);
                const int off = swz(srow, skh * 2 + j * 16);
                *(uint4*)(Ah + off) = *(uint4*)oh;
                *(uint4*)(Al + off) = *(uint4*)ol;
            }
            __syncthreads();

            #pragma unroll
            for (int kk = 0; kk < 2; ++kk) {
                short8 ah[4], al[4];
                #pragma unroll
                for (int mi = 0; mi < 4; ++mi) {
                    const int off = swz(wm + mi * 16 + lrow, kk * 64 + kg16);
                    ah[mi] = *(const short8*)(Ah + off);
                    al[mi] = *(const short8*)(Al + off);
                }
                #pragma unroll
                for (int ni = 0; ni < 4; ++ni) {
                    const int off = swz(wn + ni * 16 + lrow, kk * 64 + kg16);
                    short8 bh = *(const short8*)(Bh + off);
                    short8 bl = *(const short8*)(Bl + off);
                    #pragma unroll
                    for (int mi = 0; mi < 4; ++mi) {
                        acc[mi][ni] = __builtin_amdgcn_mfma_f32_16x16x32_bf16(al[mi], bh, acc[mi][ni], 0, 0, 0);
                        acc[mi][ni] = __builtin_amdgcn_mfma_f32_16x16x32_bf16(ah[mi], bl, acc[mi][ni], 0, 0, 0);
                        acc[mi][ni] = __builtin_amdgcn_mfma_f32_16x16x32_bf16(ah[mi], bh, acc[mi][ni], 0, 0, 0);
                    }
                }
            }
            __syncthreads();
        }

        const int r0 = bm + wm + (lane >> 4) * 4;
        const int c0 = bn + wn + (lane & 15);
        #pragma unroll
        for (int ni = 0; ni < 4; ++ni) {
            const int col = c0 + ni * 16;
            const float bv = bias[col];
            #pragma unroll
            for (int mi = 0; mi < 4; ++mi) {
                #pragma unroll
                for (int r = 0; r < 4; ++r) {
                    const int row = r0 + mi * 16 + r;
                    if (row < M) {
                        float x = tanhf(acc[mi][ni][r] + bv);
                        ushort h, l;
                        split2(x, h, l);
                        CH[(long long)row * N + col] = h;
                        CL[(long long)row * N + col] = l;
                    }
                }
            }
        }
    } else if (bid < 3264) {
        // ---- lhs -> lhsT bf16 transpose (32x32 tile in dynamic smem) ----
        float* tile = (float*)smem;              // [32][33]
        const int tid = bid - 192;
        const int sx = tid & 15;
        const int dy = (tid >> 4) % 24;
        const int b  = tid / 384;
        const int s0 = sx * 32, d0 = dy * 32;
        const int tx = threadIdx.x & 31, ty = threadIdx.x >> 5;
        const float* ip = lhs + (long long)b * S * D;
        #pragma unroll
        for (int i = 0; i < 32; i += 8)
            tile[(ty + i) * 33 + tx] = ip[(long long)(s0 + ty + i) * D + d0 + tx];
        __syncthreads();
        ushort* op = lhsT + (long long)b * S * D;
        #pragma unroll
        for (int i = 0; i < 32; i += 8)
            op[(long long)(d0 + ty + i) * S + s0 + tx] = f2bf(tile[tx * 33 + ty + i]);
    } else {
        // ---- label hi/lo split ----
        long long i = (long long)(bid - 3264) * 256 + threadIdx.x;
        if (i < nLE4) {
            float4 v = *(const float4*)(label + i * 4);
            ushort h[4], l[4];
            split2(v.x, h[0], l[0]); split2(v.y, h[1], l[1]);
            split2(v.z, h[2], l[2]); split2(v.w, h[3], l[3]);
            *(ushort4*)(labelH + i * 4) = *(ushort4*)h;
            *(ushort4*)(labelL + i * 4) = *(ushort4*)l;
        }
    }
}

// ---------------------------------------------------------------------------
// Softmax write with inlined merge (reads chunk stats pm/ps directly).
// ---------------------------------------------------------------------------
__global__ __launch_bounds__(256) void softmax_write2_kernel(
    float* __restrict__ scores, const float* __restrict__ pm,
    const float* __restrict__ ps, int L, int S, int chlen,
    ushort* __restrict__ wbf)
{
    int s = blockIdx.x * 256 + threadIdx.x;
    int c = blockIdx.y;
    int b = blockIdx.z;

    float m = -INFINITY;
    #pragma unroll
    for (int k = 0; k < SM_CH; ++k)
        m = fmaxf(m, pm[(b * SM_CH + k) * S + s]);
    float sum = 0.f;
    #pragma unroll
    for (int k = 0; k < SM_CH; ++k)
        sum += ps[(b * SM_CH + k) * S + s] * __expf(pm[(b * SM_CH + k) * S + s] - m);
    float inv = 1.f / sum;

    float* p = scores + (long long)b * L * S + s;
    ushort* q = wbf + (long long)b * L * S + s;
    int l0 = c * chlen;
    int l1 = min(L, l0 + chlen);
    for (int l = l0; l < l1; ++l) {
        float x = p[(long long)l * S];
        float v = __expf(x - m) * inv;
        p[(long long)l * S] = v;
        q[(long long)l * S] = f2bf(v);
    }
}

extern "C" void kernel_launch(void* const* d_in, const int* in_sizes, int n_in,
                              void* d_out, int out_size, void* d_ws, size_t ws_size,
                              hipStream_t stream)
{
    const int Bn = 8, S = 512, D = 768, E = 768, L = 4000;
    const float* lhs   = (const float*)d_in[0];   // [B,S,D]
    const float* label = (const float*)d_in[1];   // [L,E]
    const float* W     = (const float*)d_in[2];   // [E,D]
    const float* bias  = (const float*)d_in[3];   // [E]

    float* weights = (float*)d_out;                          // [B,L,S]
    float* attn    = (float*)d_out + (long long)Bn * L * S;  // [B,L,D]

    const long long nLE  = (long long)L * E;        // 3,072,000
    const long long nBSE = (long long)Bn * S * E;   // 3,145,728
    const long long nBDS = (long long)Bn * D * S;   // 3,145,728
    const long long nBLS = (long long)Bn * L * S;   // 16,384,000
    const long long nED  = (long long)E * D;        // 589,824

    ushort* labelH = (ushort*)d_ws;
    ushort* labelL = labelH + nLE;
    ushort* projH  = labelL + nLE;
    ushort* projL  = projH + nBSE;
    ushort* lhsT   = projL + nBSE;
    ushort* wbf    = lhsT + nBDS;
    float*  pm     = (float*)(wbf + nBLS);
    float*  ps     = pm + Bn * SM_CH * S;
    ushort* WH     = (ushort*)(ps + Bn * SM_CH * S);
    ushort* WL     = WH + nED;

    hipFuncSetAttribute((const void*)mfma_sc2,
                        hipFuncAttributeMaxDynamicSharedMemorySize, 131072);
    hipFuncSetAttribute((const void*)mfma_attn8,
                        hipFuncAttributeMaxDynamicSharedMemorySize, 98304);
    hipFuncSetAttribute((const void*)proj_prep_kernel,
                        hipFuncAttributeMaxDynamicSharedMemorySize, 65536);

    // 0) W hi/lo planes (tiny; must precede the fused proj launch)
    split_planes_kernel<<<(int)(nED / 4 + 255) / 256, 256, 0, stream>>>(
        W, WH, WL, nED / 4);

    // 1) fused: proj GEMM (192 blocks) || lhsT transpose (3072) || label
    //    split (3000) — prep soaks the CUs the GEMM leaves idle.
    proj_prep_kernel<<<6264, 256, 65536, stream>>>(
        lhs, WH, WL, projH, projL, bias,
        lhsT, label, labelH, labelL,
        Bn * S, E, D, S, D, nLE / 4);

    // 2) scores + fused per-chunk (max,sum): M=L, N=S, K=768, BK=32
    mfma_sc2<<<dim3((L + 255) / 256, S / 256, Bn), 512, 131072, stream>>>(
        labelH, labelL, projH, projL, weights, pm, ps,
        L, S, (long long)S * E, (long long)L * S);

    // 3) softmax write with inlined merge (in place, + bf16 copy)
    softmax_write2_kernel<<<dim3(S / 256, WCH, Bn), 256, 0, stream>>>(
        weights, pm, ps, L, S, (L + WCH - 1) / WCH, wbf);

    // 4) attn = wbf @ lhsT^T: M=L, N=D, K=512
    mfma_attn8<<<dim3((L + 127) / 128, D / 256, Bn), 512, 98304, stream>>>(
        wbf, lhsT, attn, L, D,
        (long long)L * S, (long long)D * S, (long long)L * D);
}